// Round 2
// baseline (860.041 us; speedup 1.0000x reference)
//
#include <hip/hip_runtime.h>
#include <hip/hip_bf16.h>

#define NB   8192   // batch
#define LL   224    // spectral bands
#define SS   25     // K*K
#define CTR  12     // center index
#define DD   128    // model dim
#define PP   6      // endmembers
#define NHH  4      // heads
#define DKK  32     // dim per head
#define HID  64     // hidden
#define XST  28     // LDS row stride for xt (16B aligned, 25 payload)
#define KST  129    // LDS row stride for keys (bank-conflict-free scores)

__device__ __forceinline__ float f_sigmoid(float x) { return 1.0f / (1.0f + __expf(-x)); }

// ---- main per-batch front kernel -------------------------------------------
// thread layout: pair = t>>7 (0: keys+q, 1: vals), d = t&127  (wave-uniform pair)
template <bool WITHQ>
__device__ __forceinline__ void gemm25(const float* __restrict__ xl,
                                       const float* __restrict__ wp,
                                       const float* __restrict__ wqp,
                                       int d, float* acc, float& accq)
{
    for (int l = 0; l < LL; ++l) {
        float w = wp[l * DD + d];
        const float* xr = xl + l * XST;
        float xv[24];
        float x24;
#pragma unroll
        for (int q4 = 0; q4 < 6; ++q4)
            *(float4*)(xv + 4 * q4) = *(const float4*)(xr + 4 * q4);
        x24 = xr[24];
#pragma unroll
        for (int s = 0; s < 24; ++s) acc[s] = fmaf(xv[s], w, acc[s]);
        acc[24] = fmaf(x24, w, acc[24]);
        if (WITHQ) accq = fmaf(xv[CTR], wqp[l * DD + d], accq);
    }
}

__global__ __launch_bounds__(256) void k1_front(
    const float* __restrict__ x,
    const float* __restrict__ wk_w, const float* __restrict__ wk_b,
    const float* __restrict__ wv_w, const float* __restrict__ wv_b,
    const float* __restrict__ wq_w, const float* __restrict__ wq_b,
    const float* __restrict__ ng_w, const float* __restrict__ ng_b,
    const float* __restrict__ f1_fw, const float* __restrict__ f1_fb,
    const float* __restrict__ f1_gw, const float* __restrict__ f1_gb,
    const float* __restrict__ s1_fw, const float* __restrict__ s1_fb,
    const float* __restrict__ s1_gw, const float* __restrict__ s1_gb,
    float* __restrict__ h1_ws, float* __restrict__ g1_ws)
{
    __shared__ float xl[LL * XST];      // 25088 B : xt[l][s] as f32
    __shared__ float keys[SS * KST];    // 12900 B
    __shared__ float qv[DD];
    __shared__ float att[NHH * SS];
    __shared__ float red[4];
    __shared__ float swv[DD];
    __shared__ float dots[256];

    const int b = blockIdx.x;
    const int t = threadIdx.x;

    // stage x[b] (L*S f32, l-major) into LDS, padded rows
    const float* xb = x + (size_t)b * (LL * SS);
    for (int i = t; i < LL * SS; i += 256) {
        int l = i / SS;
        int s = i - l * SS;
        xl[l * XST + s] = xb[i];
    }
    __syncthreads();

    const int pair = t >> 7;            // wave-uniform (waves 0,1 vs 2,3)
    const int d = t & 127;
    float acc[SS];
    float bias0 = pair ? wv_b[d] : wk_b[d];
#pragma unroll
    for (int s = 0; s < SS; ++s) acc[s] = bias0;
    float accq = wq_b[d];

    if (pair == 0) gemm25<true >(xl, wk_w, wq_w, d, acc, accq);
    else           gemm25<false>(xl, wv_w, wq_w, d, acc, accq);

    // keys + q to LDS (vals stay in pair1 registers)
    if (pair == 0) {
#pragma unroll
        for (int s = 0; s < SS; ++s) keys[s * KST + d] = acc[s];
        qv[d] = accq;
    }
    __syncthreads();

    // scores (100 values) with center mask
    if (t < NHH * SS) {
        int h = t / SS;
        int s = t - h * SS;
        float sc = 0.f;
#pragma unroll
        for (int i = 0; i < DKK; ++i)
            sc = fmaf(qv[h * DKK + i], keys[s * KST + h * DKK + i], sc);
        sc *= 0.088388347648318447f;    // 1/sqrt(128)
        if (s == CTR) sc -= 1e6f;
        att[h * SS + s] = sc;
    }
    __syncthreads();

    // softmax per head (4 threads, serial over 25)
    if (t < NHH) {
        float mx = -1e30f;
        for (int s = 0; s < SS; ++s) mx = fmaxf(mx, att[t * SS + s]);
        float sum = 0.f;
        for (int s = 0; s < SS; ++s) {
            float e = __expf(att[t * SS + s] - mx);
            att[t * SS + s] = e;
            sum += e;
        }
        float inv = 1.0f / sum;
        for (int s = 0; s < SS; ++s) att[t * SS + s] *= inv;
    }
    __syncthreads();

    // surround / central / nearby-gate / swish(ss) -- pair1 holds vals in regs
    float sur = 0.f, cen = 0.f;
    if (pair == 1) {
        int h = d >> 5;
#pragma unroll
        for (int s = 0; s < SS; ++s) sur = fmaf(att[h * SS + s], acc[s], sur);
        cen = acc[CTR];
        float term = (cen - sur) * ng_w[d];
#pragma unroll
        for (int off = 32; off > 0; off >>= 1) term += __shfl_down(term, off);
        if ((t & 63) == 0) red[t >> 6] = term;
    }
    __syncthreads();
    if (pair == 1) {
        float tot = red[2] + red[3] + ng_b[0];
        float nearby = f_sigmoid(tot);
        float ssv = cen + nearby * sur;
        swv[d] = ssv * f_sigmoid(ssv);  // swish(ss)
    }
    __syncthreads();

    // FC1: four 128->64 matvecs (f1_f, f1_g, s1_f, s1_g), one per wave
    {
        const int mi = t >> 6;          // wave-uniform
        const int j = t & 63;
        const float* W; const float* Bv;
        if      (mi == 0) { W = f1_fw; Bv = f1_fb; }
        else if (mi == 1) { W = f1_gw; Bv = f1_gb; }
        else if (mi == 2) { W = s1_fw; Bv = s1_fb; }
        else              { W = s1_gw; Bv = s1_gb; }
        float dot = Bv[j];
#pragma unroll 4
        for (int dd = 0; dd < DD; ++dd)
            dot = fmaf(swv[dd], W[dd * HID + j], dot);
        dots[t] = dot;
    }
    __syncthreads();

    // GLU -> workspace (f32)
    if (t < 64) {
        h1_ws[(size_t)b * HID + t] = dots[t] * f_sigmoid(dots[64 + t]);
    } else if (t >= 128 && t < 192) {
        int j = t - 128;
        g1_ws[(size_t)b * HID + j] = dots[t] * f_sigmoid(dots[t + 64]);
    }
}

// ---- BN stats: one block per (branch, j) column ----------------------------
__global__ __launch_bounds__(256) void k2_bn(
    const float* __restrict__ h1, const float* __restrict__ g1,
    const float* __restrict__ fg, const float* __restrict__ fb,
    const float* __restrict__ sg, const float* __restrict__ sb,
    float* __restrict__ bn)     // [af(64) cf(64) as(64) cs(64)]
{
    const int blk = blockIdx.x;       // 0..127
    const int branch = blk >> 6;
    const int j = blk & 63;
    const float* src = branch ? g1 : h1;
    const int t = threadIdx.x;
    float s = 0.f, sq = 0.f;
    for (int b = t; b < NB; b += 256) {
        float v = src[(size_t)b * HID + j];
        s += v;
        sq = fmaf(v, v, sq);
    }
#pragma unroll
    for (int off = 32; off > 0; off >>= 1) {
        s  += __shfl_down(s, off);
        sq += __shfl_down(sq, off);
    }
    __shared__ float rs[4], rq[4];
    if ((t & 63) == 0) { rs[t >> 6] = s; rq[t >> 6] = sq; }
    __syncthreads();
    if (t == 0) {
        float S1 = rs[0] + rs[1] + rs[2] + rs[3];
        float S2 = rq[0] + rq[1] + rq[2] + rq[3];
        float m   = S1 * (1.0f / NB);
        float var = S2 * (1.0f / NB) - m * m;
        float g  = branch ? sg[j] : fg[j];
        float be = branch ? sb[j] : fb[j];
        float a  = g * rsqrtf(var + 1e-5f);
        bn[branch * 128 + j]      = a;
        bn[branch * 128 + 64 + j] = be - m * a;
    }
}

// ---- tail: BN+swish, GLU 64->6, softmax/tanh, recon ------------------------
__global__ __launch_bounds__(256) void k3_back(
    const float* __restrict__ h1, const float* __restrict__ g1,
    const float* __restrict__ bn,
    const float* __restrict__ f2_fw, const float* __restrict__ f2_fb,
    const float* __restrict__ f2_gw, const float* __restrict__ f2_gb,
    const float* __restrict__ s2_fw, const float* __restrict__ s2_fb,
    const float* __restrict__ s2_gw, const float* __restrict__ s2_gb,
    const float* __restrict__ endm,
    float* __restrict__ out_recon, float* __restrict__ out_abd,
    float* __restrict__ out_es)
{
    const int b = blockIdx.x;
    const int t = threadIdx.x;
    __shared__ float hh[HID], gg[HID];
    __shared__ float logit[PP], esv[PP], coef[PP];

    if (t < HID) {
        float v = h1[(size_t)b * HID + t] * bn[t] + bn[64 + t];
        hh[t] = v * f_sigmoid(v);
    } else if (t < 2 * HID) {
        int j = t - HID;
        float v = g1[(size_t)b * HID + j] * bn[128 + j] + bn[192 + j];
        gg[j] = v * f_sigmoid(v);
    }
    __syncthreads();

    if (t < 2 * PP) {
        int br = t / PP;
        int p = t - br * PP;
        const float* src = br ? gg : hh;
        const float* fw = br ? s2_fw : f2_fw;
        const float* fbp = br ? s2_fb : f2_fb;
        const float* gw = br ? s2_gw : f2_gw;
        const float* gbp = br ? s2_gb : f2_gb;
        float df = fbp[p];
        float dg = gbp[p];
        for (int j = 0; j < HID; ++j) {
            float v = src[j];
            df = fmaf(v, fw[j * PP + p], df);
            dg = fmaf(v, gw[j * PP + p], dg);
        }
        float glu = df * f_sigmoid(dg);
        if (br == 0) {
            logit[p] = glu;
        } else {
            float e = tanhf(glu);
            esv[p] = e;
            out_es[(size_t)b * PP + p] = e;
        }
    }
    __syncthreads();

    if (t == 0) {
        float mx = -1e30f;
#pragma unroll
        for (int p = 0; p < PP; ++p) mx = fmaxf(mx, logit[p]);
        float sum = 0.f;
        float e[PP];
#pragma unroll
        for (int p = 0; p < PP; ++p) { e[p] = __expf(logit[p] - mx); sum += e[p]; }
        float inv = 1.0f / sum;
#pragma unroll
        for (int p = 0; p < PP; ++p) {
            float a = e[p] * inv;
            out_abd[(size_t)b * PP + p] = a;
            coef[p] = a * (1.0f + 0.2f * esv[p]);
        }
    }
    __syncthreads();

    if (t < LL) {
        float r = 0.f;
#pragma unroll
        for (int p = 0; p < PP; ++p)
            r = fmaf(coef[p], endm[p * LL + t], r);
        out_recon[(size_t)b * LL + t] = r;
    }
}

extern "C" void kernel_launch(void* const* d_in, const int* in_sizes, int n_in,
                              void* d_out, int out_size, void* d_ws, size_t ws_size,
                              hipStream_t stream)
{
    const float* x     = (const float*)d_in[0];
    const float* wk_w  = (const float*)d_in[1];
    const float* wk_b  = (const float*)d_in[2];
    const float* wv_w  = (const float*)d_in[3];
    const float* wv_b  = (const float*)d_in[4];
    const float* wq_w  = (const float*)d_in[5];
    const float* wq_b  = (const float*)d_in[6];
    const float* ng_w  = (const float*)d_in[7];
    const float* ng_b  = (const float*)d_in[8];
    const float* f1_fw = (const float*)d_in[9];
    const float* f1_fb = (const float*)d_in[10];
    const float* f1_gw = (const float*)d_in[11];
    const float* f1_gb = (const float*)d_in[12];
    const float* f_bng = (const float*)d_in[13];
    const float* f_bnb = (const float*)d_in[14];
    const float* f2_fw = (const float*)d_in[15];
    const float* f2_fb = (const float*)d_in[16];
    const float* f2_gw = (const float*)d_in[17];
    const float* f2_gb = (const float*)d_in[18];
    const float* s1_fw = (const float*)d_in[19];
    const float* s1_fb = (const float*)d_in[20];
    const float* s1_gw = (const float*)d_in[21];
    const float* s1_gb = (const float*)d_in[22];
    const float* s_bng = (const float*)d_in[23];
    const float* s_bnb = (const float*)d_in[24];
    const float* s2_fw = (const float*)d_in[25];
    const float* s2_fb = (const float*)d_in[26];
    const float* s2_gw = (const float*)d_in[27];
    const float* s2_gb = (const float*)d_in[28];
    const float* endm  = (const float*)d_in[29];

    float* ws    = (float*)d_ws;
    float* h1_ws = ws;                          // NB*64 f32
    float* g1_ws = ws + (size_t)NB * HID;       // NB*64 f32
    float* bn    = ws + (size_t)2 * NB * HID;   // 256 f32

    float* out       = (float*)d_out;
    float* out_recon = out;                              // NB*LL
    float* out_abd   = out + (size_t)NB * LL;            // NB*PP
    float* out_es    = out + (size_t)NB * (LL + PP);     // NB*PP

    k1_front<<<NB, 256, 0, stream>>>(x, wk_w, wk_b, wv_w, wv_b, wq_w, wq_b,
                                     ng_w, ng_b, f1_fw, f1_fb, f1_gw, f1_gb,
                                     s1_fw, s1_fb, s1_gw, s1_gb, h1_ws, g1_ws);
    k2_bn<<<128, 256, 0, stream>>>(h1_ws, g1_ws, f_bng, f_bnb, s_bng, s_bnb, bn);
    k3_back<<<NB, 256, 0, stream>>>(h1_ws, g1_ws, bn,
                                    f2_fw, f2_fb, f2_gw, f2_gb,
                                    s2_fw, s2_fb, s2_gw, s2_gb,
                                    endm, out_recon, out_abd, out_es);
}

// Round 3
// 623.640 us; speedup vs baseline: 1.3791x; 1.3791x over previous
//
#include <hip/hip_runtime.h>
#include <hip/hip_bf16.h>

typedef unsigned short ushort;
typedef __bf16 bfrag_t __attribute__((ext_vector_type(8)));   // 8 bf16 = 4 VGPRs
typedef float  ffrag_t __attribute__((ext_vector_type(4)));   // 4 f32 acc

#define NB   8192   // batch
#define LL   224    // spectral bands
#define SS   25     // K*K
#define CTR  12     // center index
#define DD   128    // model dim
#define PP   6      // endmembers
#define HID  64     // hidden
#define GPB  2      // batches per k1 block
#define KST  129    // keys/vals LDS row stride (f32)
#define NKC  7      // K-chunks of 32 (224/32)
#define NMT  4      // M-tiles of 16 (2 batches * 32 rows)
// packed weight matrix: 7 kc * 8 nt * 64 lanes * 8 bf16 = 28672 elems
#define WPK_ELEMS 28672

__device__ __forceinline__ float f_sigmoid(float x) { return 1.0f / (1.0f + __expf(-x)); }
__device__ __forceinline__ ushort f2bf(float f) {
    __hip_bfloat16 h = __float2bfloat16(f);
    return *reinterpret_cast<ushort*>(&h);
}

// ---- k0: pack wk/wv into bf16 B-fragment order -----------------------------
// B-frag for mfma_f32_16x16x32_bf16: lane holds B[k = kc*32+(lane>>4)*8+j][n = nt*16+(lane&15)]
__global__ __launch_bounds__(256) void k0_pack(
    const float* __restrict__ wk_w, const float* __restrict__ wv_w,
    ushort* __restrict__ wpack)
{
    const int mat = blockIdx.x;                 // 0=K, 1=V
    const float* w = mat ? wv_w : wk_w;
    for (int idx = threadIdx.x; idx < WPK_ELEMS; idx += 256) {
        int j    = idx & 7;
        int lane = (idx >> 3) & 63;
        int f    = idx >> 9;                    // 0..55
        int kc   = f >> 3;
        int nt   = f & 7;
        int k = kc * 32 + ((lane >> 4) << 3) + j;
        int n = nt * 16 + (lane & 15);
        wpack[mat * WPK_ELEMS + idx] = f2bf(w[k * DD + n]);
    }
}

// ---- k1: MFMA front: keys/vals GEMM + attention + gate + FC1/GLU -----------
__global__ __launch_bounds__(256) void k1_front(
    const float* __restrict__ x,
    const ushort* __restrict__ wpack,
    const float* __restrict__ wk_b, const float* __restrict__ wv_b,
    const float* __restrict__ wq_w, const float* __restrict__ wq_b,
    const float* __restrict__ ng_w, const float* __restrict__ ng_b,
    const float* __restrict__ f1_fw, const float* __restrict__ f1_fb,
    const float* __restrict__ f1_gw, const float* __restrict__ f1_gb,
    const float* __restrict__ s1_fw, const float* __restrict__ s1_fb,
    const float* __restrict__ s1_gw, const float* __restrict__ s1_gb,
    float* __restrict__ h1_ws, float* __restrict__ g1_ws)
{
    // A fragments: 4 mt * 7 kc * 64 lanes * 8 bf16 = 14336 ushort = 28672 B
    // reused after GEMM as vals[2][25][129] f32 (25800 B <= 28672)
    __shared__ ushort alds[NMT * NKC * 64 * 8];
    __shared__ float  keys[GPB * SS * KST];     // 25800 B
    __shared__ float  qv[GPB * DD];
    __shared__ float  att[GPB * 4 * SS];
    __shared__ float  swv[GPB * DD];
    __shared__ float  dots[GPB * 4 * HID];
    __shared__ float  red[4];

    const int t    = threadIdx.x;
    const int b0   = blockIdx.x * GPB;
    const int wave = t >> 6;
    const int lane = t & 63;

    // ---- phase 1: stage x as bf16 A-fragments -----------------------------
    // A[r = g*32+s][k = l] = x[b0+g][l*25+s]; pad rows 25..31 left as garbage
    // (row-independent in A*B; their outputs are dropped).
    for (int g = 0; g < GPB; ++g) {
        const float* xb = x + (size_t)(b0 + g) * (LL * SS);
        for (int i = t; i < LL * SS; i += 256) {
            int l = i / SS;
            int s = i - l * SS;
            int r  = g * 32 + s;
            int mt = r >> 4;
            int kc = l >> 5;
            int ln = (r & 15) | (((l >> 3) & 3) << 4);
            int j  = l & 7;
            alds[((mt * NKC + kc) * 64 + ln) * 8 + j] = f2bf(xb[i]);
        }
    }
    __syncthreads();

    // ---- phase 2: GEMM. wave = {K,V} x {col half} -------------------------
    const int mat = wave >> 1;                  // 0=keys, 1=vals
    const int ch  = wave & 1;                   // column half (64 cols)
    const ushort* wp = wpack + mat * WPK_ELEMS;
    const float* bvec = mat ? wv_b : wk_b;

    ffrag_t acc[NMT][4];
#pragma unroll
    for (int mt = 0; mt < NMT; ++mt)
#pragma unroll
        for (int nt = 0; nt < 4; ++nt) acc[mt][nt] = ffrag_t{0.f, 0.f, 0.f, 0.f};

    float bias[4];
#pragma unroll
    for (int nt = 0; nt < 4; ++nt)
        bias[nt] = bvec[(ch * 4 + nt) * 16 + (lane & 15)];

    for (int kc = 0; kc < NKC; ++kc) {
        bfrag_t bf[4];
#pragma unroll
        for (int nt = 0; nt < 4; ++nt)
            bf[nt] = *(const bfrag_t*)(wp + ((kc * 8 + ch * 4 + nt) * 64 + lane) * 8);
#pragma unroll
        for (int mt = 0; mt < NMT; ++mt) {
            bfrag_t af = *(const bfrag_t*)(alds + ((mt * NKC + kc) * 64 + lane) * 8);
#pragma unroll
            for (int nt = 0; nt < 4; ++nt)
                acc[mt][nt] = __builtin_amdgcn_mfma_f32_16x16x32_bf16(af, bf[nt], acc[mt][nt], 0, 0, 0);
        }
    }
    __syncthreads();   // all A reads done; alds may be overwritten by vals

    // ---- phase 2b: write C tiles to LDS -----------------------------------
    // C/D layout: col = lane&15, row = (lane>>4)*4 + reg
    float* cdst = mat ? (float*)alds : keys;    // vals reuse alds region
#pragma unroll
    for (int mt = 0; mt < NMT; ++mt) {
#pragma unroll
        for (int nt = 0; nt < 4; ++nt) {
            int n = (ch * 4 + nt) * 16 + (lane & 15);
#pragma unroll
            for (int reg = 0; reg < 4; ++reg) {
                int r = mt * 16 + ((lane >> 4) << 2) + reg;
                int g = r >> 5;
                int s = r & 31;
                if (s < SS)
                    cdst[(g * SS + s) * KST + n] = acc[mt][nt][reg] + bias[nt];
            }
        }
    }

    // ---- phase 3: q = xt[CTR] @ wq + b (f32 VALU) -------------------------
    {
        const int g = t >> 7;
        const int d = t & 127;
        const float* xq = x + (size_t)(b0 + g) * (LL * SS) + CTR;
        const float* wqd = wq_w + d;
        float q0 = 0.f, q1 = 0.f, q2 = 0.f, q3 = 0.f;
        for (int l = 0; l < LL; l += 4) {
            q0 = fmaf(xq[(l + 0) * SS], wqd[(l + 0) * DD], q0);
            q1 = fmaf(xq[(l + 1) * SS], wqd[(l + 1) * DD], q1);
            q2 = fmaf(xq[(l + 2) * SS], wqd[(l + 2) * DD], q2);
            q3 = fmaf(xq[(l + 3) * SS], wqd[(l + 3) * DD], q3);
        }
        qv[t] = wq_b[d] + (q0 + q1) + (q2 + q3);
    }
    __syncthreads();   // keys, vals, qv ready

    const float* vals = (const float*)alds;

    // ---- phase 4: scores (2 g * 4 h * 25 s = 200) -------------------------
    if (t < GPB * 4 * SS) {
        int g  = t >= 100;
        int tt = t - g * 100;
        int h  = tt / SS;
        int s  = tt - h * SS;
        const float* kr = keys + (g * SS + s) * KST + h * 32;
        const float* qr = qv + g * DD + h * 32;
        float a0 = 0.f, a1 = 0.f, a2 = 0.f, a3 = 0.f;
#pragma unroll
        for (int i = 0; i < 32; i += 4) {
            a0 = fmaf(qr[i + 0], kr[i + 0], a0);
            a1 = fmaf(qr[i + 1], kr[i + 1], a1);
            a2 = fmaf(qr[i + 2], kr[i + 2], a2);
            a3 = fmaf(qr[i + 3], kr[i + 3], a3);
        }
        float sc = ((a0 + a1) + (a2 + a3)) * 0.088388347648318447f;
        if (s == CTR) sc -= 1e6f;
        att[(g * 4 + h) * SS + s] = sc;
    }
    __syncthreads();

    // ---- phase 5: softmax per (g,h) ---------------------------------------
    if (t < GPB * 4) {
        float* ar = att + t * SS;
        float mx = -1e30f;
        for (int s = 0; s < SS; ++s) mx = fmaxf(mx, ar[s]);
        float sum = 0.f;
        for (int s = 0; s < SS; ++s) { float e = __expf(ar[s] - mx); ar[s] = e; sum += e; }
        float inv = 1.0f / sum;
        for (int s = 0; s < SS; ++s) ar[s] *= inv;
    }
    __syncthreads();

    // ---- phase 6: surround / central / nearby gate / swish ----------------
    {
        const int g = t >> 7;
        const int d = t & 127;
        const int h = d >> 5;
        const float* vrow = vals + g * SS * KST + d;
        const float* arow = att + (g * 4 + h) * SS;
        float s0 = 0.f, s1 = 0.f;
#pragma unroll
        for (int s = 0; s < 24; s += 2) {
            s0 = fmaf(arow[s],     vrow[s * KST],       s0);
            s1 = fmaf(arow[s + 1], vrow[(s + 1) * KST], s1);
        }
        float sur = fmaf(arow[24], vrow[24 * KST], s0 + s1);
        float cen = vrow[CTR * KST];
        float term = (cen - sur) * ng_w[d];
#pragma unroll
        for (int off = 32; off > 0; off >>= 1) term += __shfl_down(term, off);
        if (lane == 0) red[wave] = term;
        __syncthreads();
        float tot = red[g * 2] + red[g * 2 + 1] + ng_b[0];
        float nearby = f_sigmoid(tot);
        float ssv = cen + nearby * sur;
        swv[t] = ssv * f_sigmoid(ssv);
    }
    __syncthreads();

    // ---- phase 7: FC1 (8 matvecs 128->64 over 4 waves, 2 each) ------------
    {
        const int g = wave >> 1;
        const int u = wave & 1;
        const float* sv = swv + g * DD;
#pragma unroll
        for (int mi = 0; mi < 2; ++mi) {
            int m = u * 2 + mi;                 // 0:f1_f 1:f1_g 2:s1_f 3:s1_g
            const float* W;  const float* Bv;
            if      (m == 0) { W = f1_fw; Bv = f1_fb; }
            else if (m == 1) { W = f1_gw; Bv = f1_gb; }
            else if (m == 2) { W = s1_fw; Bv = s1_fb; }
            else             { W = s1_gw; Bv = s1_gb; }
            const float* Wj = W + lane;
            float d0 = 0.f, d1 = 0.f;
            for (int dd = 0; dd < DD; dd += 2) {
                d0 = fmaf(sv[dd],     Wj[dd * HID],       d0);
                d1 = fmaf(sv[dd + 1], Wj[(dd + 1) * HID], d1);
            }
            dots[(g * 4 + m) * HID + lane] = Bv[lane] + d0 + d1;
        }
    }
    __syncthreads();

    // ---- phase 8: GLU -> workspace ----------------------------------------
    {
        const int g  = t >> 7;
        const int br = (t >> 6) & 1;
        const int j  = t & 63;
        float a  = dots[(g * 4 + br * 2) * HID + j];
        float gt = dots[(g * 4 + br * 2 + 1) * HID + j];
        float hv = a * f_sigmoid(gt);
        float* dst = br ? g1_ws : h1_ws;
        dst[(size_t)(b0 + g) * HID + j] = hv;
    }
}

// ---- k2: BN stats: one block per (branch, j) column ------------------------
__global__ __launch_bounds__(256) void k2_bn(
    const float* __restrict__ h1, const float* __restrict__ g1,
    const float* __restrict__ fg, const float* __restrict__ fb,
    const float* __restrict__ sg, const float* __restrict__ sb,
    float* __restrict__ bn)     // [af(64) cf(64) as(64) cs(64)]
{
    const int blk = blockIdx.x;       // 0..127
    const int branch = blk >> 6;
    const int j = blk & 63;
    const float* src = branch ? g1 : h1;
    const int t = threadIdx.x;
    float s = 0.f, sq = 0.f;
    for (int b = t; b < NB; b += 256) {
        float v = src[(size_t)b * HID + j];
        s += v;
        sq = fmaf(v, v, sq);
    }
#pragma unroll
    for (int off = 32; off > 0; off >>= 1) {
        s  += __shfl_down(s, off);
        sq += __shfl_down(sq, off);
    }
    __shared__ float rs[4], rq[4];
    if ((t & 63) == 0) { rs[t >> 6] = s; rq[t >> 6] = sq; }
    __syncthreads();
    if (t == 0) {
        float S1 = rs[0] + rs[1] + rs[2] + rs[3];
        float S2 = rq[0] + rq[1] + rq[2] + rq[3];
        float m   = S1 * (1.0f / NB);
        float var = S2 * (1.0f / NB) - m * m;
        float g  = branch ? sg[j] : fg[j];
        float be = branch ? sb[j] : fb[j];
        float a  = g * rsqrtf(var + 1e-5f);
        bn[branch * 128 + j]      = a;
        bn[branch * 128 + 64 + j] = be - m * a;
    }
}

// ---- k3: tail, 32 batches per block ----------------------------------------
#define K3G 32
__global__ __launch_bounds__(256) void k3_back(
    const float* __restrict__ h1, const float* __restrict__ g1,
    const float* __restrict__ bn,
    const float* __restrict__ f2_fw, const float* __restrict__ f2_fb,
    const float* __restrict__ f2_gw, const float* __restrict__ f2_gb,
    const float* __restrict__ s2_fw, const float* __restrict__ s2_fb,
    const float* __restrict__ s2_gw, const float* __restrict__ s2_gb,
    const float* __restrict__ endm,
    float* __restrict__ out_recon, float* __restrict__ out_abd,
    float* __restrict__ out_es)
{
    const int B0 = blockIdx.x * K3G;
    const int t = threadIdx.x;
    __shared__ float bnl[256];
    __shared__ float endl[PP * LL];
    __shared__ float hh[K3G * 65], gg[K3G * 65];
    __shared__ float logit[K3G * 8], esv[K3G * 8], coef[K3G * 8];

    bnl[t] = bn[t];
    for (int i = t; i < PP * LL; i += 256) endl[i] = endm[i];
    __syncthreads();

    // BN + swish
    for (int i = t; i < K3G * HID; i += 256) {
        int ba = i >> 6, j = i & 63;
        float v1 = h1[(size_t)(B0 + ba) * HID + j] * bnl[j] + bnl[64 + j];
        hh[ba * 65 + j] = v1 * f_sigmoid(v1);
        float v2 = g1[(size_t)(B0 + ba) * HID + j] * bnl[128 + j] + bnl[192 + j];
        gg[ba * 65 + j] = v2 * f_sigmoid(v2);
    }
    __syncthreads();

    // GLU 64->6 for both branches
    for (int i = t; i < K3G * 2 * PP; i += 256) {
        int ba = i / (2 * PP);
        int rr = i - ba * (2 * PP);
        int br = rr / PP;
        int p  = rr - br * PP;
        const float* src = (br ? gg : hh) + ba * 65;
        const float* fw  = br ? s2_fw : f2_fw;
        const float* fbp = br ? s2_fb : f2_fb;
        const float* gw  = br ? s2_gw : f2_gw;
        const float* gbp = br ? s2_gb : f2_gb;
        float df = fbp[p], dg = gbp[p];
        for (int j = 0; j < HID; ++j) {
            float v = src[j];
            df = fmaf(v, fw[j * PP + p], df);
            dg = fmaf(v, gw[j * PP + p], dg);
        }
        float glu = df * f_sigmoid(dg);
        if (br == 0) {
            logit[ba * 8 + p] = glu;
        } else {
            float e = tanhf(glu);
            esv[ba * 8 + p] = e;
            out_es[(size_t)(B0 + ba) * PP + p] = e;
        }
    }
    __syncthreads();

    // softmax(6) + coef
    if (t < K3G) {
        float mx = -1e30f;
#pragma unroll
        for (int p = 0; p < PP; ++p) mx = fmaxf(mx, logit[t * 8 + p]);
        float e[PP]; float sum = 0.f;
#pragma unroll
        for (int p = 0; p < PP; ++p) { e[p] = __expf(logit[t * 8 + p] - mx); sum += e[p]; }
        float inv = 1.0f / sum;
#pragma unroll
        for (int p = 0; p < PP; ++p) {
            float a = e[p] * inv;
            out_abd[(size_t)(B0 + t) * PP + p] = a;
            coef[t * 8 + p] = a * (1.0f + 0.2f * esv[t * 8 + p]);
        }
    }
    __syncthreads();

    // recon
    for (int i = t; i < K3G * LL; i += 256) {
        int ba = i / LL;
        int l  = i - ba * LL;
        float r = 0.f;
#pragma unroll
        for (int p = 0; p < PP; ++p)
            r = fmaf(coef[ba * 8 + p], endl[p * LL + l], r);
        out_recon[(size_t)(B0 + ba) * LL + l] = r;
    }
}

extern "C" void kernel_launch(void* const* d_in, const int* in_sizes, int n_in,
                              void* d_out, int out_size, void* d_ws, size_t ws_size,
                              hipStream_t stream)
{
    const float* x     = (const float*)d_in[0];
    const float* wk_w  = (const float*)d_in[1];
    const float* wk_b  = (const float*)d_in[2];
    const float* wv_w  = (const float*)d_in[3];
    const float* wv_b  = (const float*)d_in[4];
    const float* wq_w  = (const float*)d_in[5];
    const float* wq_b  = (const float*)d_in[6];
    const float* ng_w  = (const float*)d_in[7];
    const float* ng_b  = (const float*)d_in[8];
    const float* f1_fw = (const float*)d_in[9];
    const float* f1_fb = (const float*)d_in[10];
    const float* f1_gw = (const float*)d_in[11];
    const float* f1_gb = (const float*)d_in[12];
    const float* f_bng = (const float*)d_in[13];
    const float* f_bnb = (const float*)d_in[14];
    const float* f2_fw = (const float*)d_in[15];
    const float* f2_fb = (const float*)d_in[16];
    const float* f2_gw = (const float*)d_in[17];
    const float* f2_gb = (const float*)d_in[18];
    const float* s1_fw = (const float*)d_in[19];
    const float* s1_fb = (const float*)d_in[20];
    const float* s1_gw = (const float*)d_in[21];
    const float* s1_gb = (const float*)d_in[22];
    const float* s_bng = (const float*)d_in[23];
    const float* s_bnb = (const float*)d_in[24];
    const float* s2_fw = (const float*)d_in[25];
    const float* s2_fb = (const float*)d_in[26];
    const float* s2_gw = (const float*)d_in[27];
    const float* s2_gb = (const float*)d_in[28];
    const float* endm  = (const float*)d_in[29];

    float* ws    = (float*)d_ws;
    float* h1_ws = ws;                          // NB*64 f32
    float* g1_ws = ws + (size_t)NB * HID;       // NB*64 f32
    float* bn    = ws + (size_t)2 * NB * HID;   // 256 f32
    ushort* wpack = (ushort*)(ws + (size_t)2 * NB * HID + 256);  // 2*28672 bf16

    float* out       = (float*)d_out;
    float* out_recon = out;                              // NB*LL
    float* out_abd   = out + (size_t)NB * LL;            // NB*PP
    float* out_es    = out + (size_t)NB * (LL + PP);     // NB*PP

    k0_pack<<<2, 256, 0, stream>>>(wk_w, wv_w, wpack);
    k1_front<<<NB / GPB, 256, 0, stream>>>(x, wpack, wk_b, wv_b, wq_w, wq_b,
                                           ng_w, ng_b, f1_fw, f1_fb, f1_gw, f1_gb,
                                           s1_fw, s1_fb, s1_gw, s1_gb, h1_ws, g1_ws);
    k2_bn<<<128, 256, 0, stream>>>(h1_ws, g1_ws, f_bng, f_bnb, s_bng, s_bnb, bn);
    k3_back<<<NB / K3G, 256, 0, stream>>>(h1_ws, g1_ws, bn,
                                          f2_fw, f2_fb, f2_gw, f2_gb,
                                          s2_fw, s2_fb, s2_gw, s2_gb,
                                          endm, out_recon, out_abd, out_es);
}

// Round 4
// 610.857 us; speedup vs baseline: 1.4079x; 1.0209x over previous
//
#include <hip/hip_runtime.h>
#include <hip/hip_bf16.h>

typedef unsigned short ushort;
typedef unsigned int   uint;
typedef __bf16 bfrag_t __attribute__((ext_vector_type(8)));   // 8 bf16 = 4 VGPRs
typedef float  ffrag_t __attribute__((ext_vector_type(4)));   // 4 f32 acc

#define NB   8192   // batch
#define LL   224    // spectral bands
#define SS   25     // K*K
#define CTR  12     // center index
#define DD   128    // model dim
#define PP   6      // endmembers
#define HID  64     // hidden
#define GPB  2      // batches per k1 block
#define NKC  7      // K-chunks of 32 (224/32)
#define NMT  4      // M-tiles of 16 (2 batches * 32 rows)
#define NNT  24     // n-tiles of 16 (384 cols = wk|wv|wq)
#define VST  130    // bf16 LDS row stride for keys/vals
// packed combined weights: 7 kc * 24 nt * 64 lanes * 8 = 86016 ushort
#define WPK_ELEMS (NKC * NNT * 64 * 8)

__device__ __forceinline__ float f_sigmoid(float x) { return 1.0f / (1.0f + __expf(-x)); }
__device__ __forceinline__ ushort f2bf(float f) {
    __hip_bfloat16 h = __float2bfloat16(f);
    ushort u; __builtin_memcpy(&u, &h, 2); return u;
}
__device__ __forceinline__ float bfu2f(ushort u) {
    uint v = ((uint)u) << 16; float f; __builtin_memcpy(&f, &v, 4); return f;
}

// ---- k0: pack [wk|wv|wq] into bf16 B-fragment order, one block per n-tile --
// B-frag: lane holds B[k = kc*32+(lane>>4)*8+j][n = nt*16+(lane&15)]
__global__ __launch_bounds__(256) void k0_pack(
    const float* __restrict__ wk_w, const float* __restrict__ wv_w,
    const float* __restrict__ wq_w, ushort* __restrict__ wpack)
{
    const int nt  = blockIdx.x;                 // 0..23
    const int mat = nt >> 3;
    const float* w = mat == 0 ? wk_w : (mat == 1 ? wv_w : wq_w);
    const int cb = (nt & 7) * 16;
    for (int e = threadIdx.x; e < NKC * 64 * 8; e += 256) {
        int j    = e & 7;
        int lane = (e >> 3) & 63;
        int kc   = e >> 9;
        int k = kc * 32 + ((lane >> 4) << 3) + j;
        int c = cb + (lane & 15);
        wpack[((kc * NNT + nt) * 64 + lane) * 8 + j] = f2bf(w[k * DD + c]);
    }
}

// ---- k1: MFMA front: K/V/Q GEMM + attention + gate + FC1/GLU ---------------
__global__ __launch_bounds__(256) void k1_front(
    const float* __restrict__ x,
    const ushort* __restrict__ wpack,
    const float* __restrict__ wk_b, const float* __restrict__ wv_b,
    const float* __restrict__ wq_b,
    const float* __restrict__ ng_w, const float* __restrict__ ng_b,
    const float* __restrict__ f1_fw, const float* __restrict__ f1_fb,
    const float* __restrict__ f1_gw, const float* __restrict__ f1_gb,
    const float* __restrict__ s1_fw, const float* __restrict__ s1_fb,
    const float* __restrict__ s1_gw, const float* __restrict__ s1_gb,
    float* __restrict__ h1_ws, float* __restrict__ g1_ws)
{
    // A fragments: 4 mt * 7 kc * 64 lanes * 8 = 14336 ushort = 28672 B
    // reused after GEMM as vals_b[2*25*130] bf16 (6500 ushort)
    __shared__ ushort alds[NMT * NKC * 64 * 8];
    __shared__ ushort keys_b[GPB * SS * VST];   // 13000 B
    __shared__ float  qv[GPB * DD];
    __shared__ float  att[GPB * 4 * SS];
    __shared__ float  swv[GPB * DD];
    __shared__ float  dots[GPB * 4 * HID];
    __shared__ float  red[4];

    const int t    = threadIdx.x;
    const int b0   = blockIdx.x * GPB;
    const int wave = t >> 6;
    const int lane = t & 63;

    // ---- phase 1: stage x as bf16 A-fragments (paired b32 writes) ---------
    // A[r = g*32+s][k = l] = x[b0+g][l*25+s]; pad rows 25..31 garbage (row-indep)
    for (int g = 0; g < GPB; ++g) {
        const float* xb = x + (size_t)(b0 + g) * (LL * SS);
        for (int p = t; p < (LL / 2) * SS; p += 256) {
            int lp = p / SS;                    // 0..111
            int s  = p - lp * SS;
            int l  = lp * 2;                    // even
            float x0 = xb[l * SS + s];
            float x1 = xb[(l + 1) * SS + s];
            uint pk = (uint)f2bf(x0) | ((uint)f2bf(x1) << 16);
            int r  = g * 32 + s;
            int mt = r >> 4;
            int ln = (r & 15) | (((l >> 3) & 3) << 4);
            int j  = l & 7;                     // even
            ((uint*)alds)[(((mt * NKC + (l >> 5)) * 64 + ln) * 8 + j) >> 1] = pk;
        }
    }
    __syncthreads();

    // ---- phase 2: GEMM. wave w covers nt = {w, w+4, w+8, w+12, w+16, w+20} -
    // ni 0,1 -> wk; ni 2,3 -> wv; ni 4,5 -> wq (only mt0/mt2 = rows 12,44)
    ffrag_t acc[4][NMT];
    ffrag_t accq[2][2];
#pragma unroll
    for (int ni = 0; ni < 4; ++ni)
#pragma unroll
        for (int mt = 0; mt < NMT; ++mt) acc[ni][mt] = ffrag_t{0.f, 0.f, 0.f, 0.f};
#pragma unroll
    for (int i = 0; i < 2; ++i)
#pragma unroll
        for (int mi = 0; mi < 2; ++mi) accq[i][mi] = ffrag_t{0.f, 0.f, 0.f, 0.f};

    for (int kc = 0; kc < NKC; ++kc) {
        bfrag_t bf[6];
#pragma unroll
        for (int ni = 0; ni < 6; ++ni) {
            int nt = wave + 4 * ni;
            bf[ni] = *(const bfrag_t*)(wpack + ((kc * NNT + nt) * 64 + lane) * 8);
        }
        bfrag_t af[NMT];
#pragma unroll
        for (int mt = 0; mt < NMT; ++mt)
            af[mt] = *(const bfrag_t*)(alds + ((mt * NKC + kc) * 64 + lane) * 8);
#pragma unroll
        for (int ni = 0; ni < 4; ++ni)
#pragma unroll
            for (int mt = 0; mt < NMT; ++mt)
                acc[ni][mt] = __builtin_amdgcn_mfma_f32_16x16x32_bf16(af[mt], bf[ni], acc[ni][mt], 0, 0, 0);
#pragma unroll
        for (int i = 0; i < 2; ++i)
#pragma unroll
            for (int mi = 0; mi < 2; ++mi)
                accq[i][mi] = __builtin_amdgcn_mfma_f32_16x16x32_bf16(af[2 * mi], bf[4 + i], accq[i][mi], 0, 0, 0);
    }

    float bias[4];
#pragma unroll
    for (int ni = 0; ni < 4; ++ni) {
        int nt = wave + 4 * ni;
        const float* bv = (nt < 8) ? wk_b : wv_b;
        bias[ni] = bv[(nt & 7) * 16 + (lane & 15)];
    }
    __syncthreads();   // A-frag reads done; alds may become vals_b

    // ---- phase 2b: C tiles -> bf16 LDS ------------------------------------
    // C/D layout: col = lane&15, row = (lane>>4)*4 + reg
    ushort* vals_b = alds;
#pragma unroll
    for (int ni = 0; ni < 4; ++ni) {
        int nt = wave + 4 * ni;
        ushort* dst = (nt < 8) ? keys_b : vals_b;
        int c = (nt & 7) * 16 + (lane & 15);
#pragma unroll
        for (int mt = 0; mt < NMT; ++mt) {
#pragma unroll
            for (int reg = 0; reg < 4; ++reg) {
                int r = mt * 16 + ((lane >> 4) << 2) + reg;
                int g = r >> 5;
                int s = r & 31;
                if (s < SS)
                    dst[(g * SS + s) * VST + c] = f2bf(acc[ni][mt][reg] + bias[ni]);
            }
        }
    }
    if ((lane >> 4) == 3) {                     // rows 12 (mt0) / 44 (mt2), reg 0
#pragma unroll
        for (int i = 0; i < 2; ++i) {
            int nt = wave + 16 + 4 * i;
            int c = (nt & 7) * 16 + (lane & 15);
#pragma unroll
            for (int mi = 0; mi < 2; ++mi)      // mi = g
                qv[mi * DD + c] = accq[i][mi][0] + wq_b[c];
        }
    }
    __syncthreads();

    // ---- phase 4: scores (2 g * 4 h * 25 s = 200) -------------------------
    if (t < GPB * 4 * SS) {
        int g  = t >= 100;
        int tt = t - g * 100;
        int h  = tt / SS;
        int s  = tt - h * SS;
        const ushort* kr = keys_b + (g * SS + s) * VST + h * 32;
        const float* qr = qv + g * DD + h * 32;
        float a0 = 0.f, a1 = 0.f, a2 = 0.f, a3 = 0.f;
#pragma unroll
        for (int i = 0; i < 32; i += 4) {
            a0 = fmaf(qr[i + 0], bfu2f(kr[i + 0]), a0);
            a1 = fmaf(qr[i + 1], bfu2f(kr[i + 1]), a1);
            a2 = fmaf(qr[i + 2], bfu2f(kr[i + 2]), a2);
            a3 = fmaf(qr[i + 3], bfu2f(kr[i + 3]), a3);
        }
        float sc = ((a0 + a1) + (a2 + a3)) * 0.088388347648318447f;
        if (s == CTR) sc -= 1e6f;
        att[(g * 4 + h) * SS + s] = sc;
    }
    __syncthreads();

    // ---- phase 5: softmax per (g,h) ---------------------------------------
    if (t < GPB * 4) {
        float* ar = att + t * SS;
        float mx = -1e30f;
        for (int s = 0; s < SS; ++s) mx = fmaxf(mx, ar[s]);
        float sum = 0.f;
        for (int s = 0; s < SS; ++s) { float e = __expf(ar[s] - mx); ar[s] = e; sum += e; }
        float inv = 1.0f / sum;
        for (int s = 0; s < SS; ++s) ar[s] *= inv;
    }
    __syncthreads();

    // ---- phase 6: surround / central / nearby gate / swish ----------------
    {
        const int g = t >> 7;
        const int d = t & 127;
        const int h = d >> 5;
        const ushort* vrow = vals_b + g * SS * VST + d;
        const float* arow = att + (g * 4 + h) * SS;
        float s0 = 0.f, s1 = 0.f;
#pragma unroll
        for (int s = 0; s < 24; s += 2) {
            s0 = fmaf(arow[s],     bfu2f(vrow[s * VST]),       s0);
            s1 = fmaf(arow[s + 1], bfu2f(vrow[(s + 1) * VST]), s1);
        }
        float sur = fmaf(arow[24], bfu2f(vrow[24 * VST]), s0 + s1);
        float cen = bfu2f(vrow[CTR * VST]);
        float term = (cen - sur) * ng_w[d];
#pragma unroll
        for (int off = 32; off > 0; off >>= 1) term += __shfl_down(term, off);
        if (lane == 0) red[wave] = term;
        __syncthreads();
        float tot = red[g * 2] + red[g * 2 + 1] + ng_b[0];
        float nearby = f_sigmoid(tot);
        float ssv = cen + nearby * sur;
        swv[t] = ssv * f_sigmoid(ssv);
    }
    __syncthreads();

    // ---- phase 7: FC1 (8 matvecs 128->64 over 4 waves, 2 each) ------------
    {
        const int g = wave >> 1;
        const int u = wave & 1;
        const float* sv = swv + g * DD;
#pragma unroll
        for (int mi = 0; mi < 2; ++mi) {
            int m = u * 2 + mi;                 // 0:f1_f 1:f1_g 2:s1_f 3:s1_g
            const float* W;  const float* Bv;
            if      (m == 0) { W = f1_fw; Bv = f1_fb; }
            else if (m == 1) { W = f1_gw; Bv = f1_gb; }
            else if (m == 2) { W = s1_fw; Bv = s1_fb; }
            else             { W = s1_gw; Bv = s1_gb; }
            const float* Wj = W + lane;
            float d0 = 0.f, d1 = 0.f, d2 = 0.f, d3 = 0.f;
            for (int q4 = 0; q4 < DD / 4; ++q4) {
                float4 s4 = *(const float4*)(sv + q4 * 4);
                d0 = fmaf(s4.x, Wj[(q4 * 4 + 0) * HID], d0);
                d1 = fmaf(s4.y, Wj[(q4 * 4 + 1) * HID], d1);
                d2 = fmaf(s4.z, Wj[(q4 * 4 + 2) * HID], d2);
                d3 = fmaf(s4.w, Wj[(q4 * 4 + 3) * HID], d3);
            }
            dots[(g * 4 + m) * HID + lane] = Bv[lane] + (d0 + d1) + (d2 + d3);
        }
    }
    __syncthreads();

    // ---- phase 8: GLU -> workspace ----------------------------------------
    {
        const int g  = t >> 7;
        const int br = (t >> 6) & 1;
        const int j  = t & 63;
        float a  = dots[(g * 4 + br * 2) * HID + j];
        float gt = dots[(g * 4 + br * 2 + 1) * HID + j];
        float hv = a * f_sigmoid(gt);
        float* dst = br ? g1_ws : h1_ws;
        dst[(size_t)(b0 + g) * HID + j] = hv;
    }
}

// ---- k2a: per-chunk partial sums (coalesced) -------------------------------
__global__ __launch_bounds__(256) void k2a_part(
    const float* __restrict__ h1, const float* __restrict__ g1,
    float* __restrict__ part)   // [2][32][128]: sum(64) | sumsq(64)
{
    const int br    = blockIdx.x >> 5;
    const int chunk = blockIdx.x & 31;
    const float* src = br ? g1 : h1;
    const int t = threadIdx.x;
    const int w = t >> 6;
    const int j = t & 63;
    const int base = chunk * 256;
    float s = 0.f, sq = 0.f;
    for (int i = 0; i < 64; ++i) {
        float v = src[(size_t)(base + i * 4 + w) * HID + j];
        s += v;
        sq = fmaf(v, v, sq);
    }
    __shared__ float ls[4][64], lq[4][64];
    ls[w][j] = s; lq[w][j] = sq;
    __syncthreads();
    if (t < 64) {
        float S = ls[0][t] + ls[1][t] + ls[2][t] + ls[3][t];
        float Q = lq[0][t] + lq[1][t] + lq[2][t] + lq[3][t];
        float* pr = part + (br * 32 + chunk) * 128;
        pr[t]      = S;
        pr[64 + t] = Q;
    }
}

// ---- k2b: finalize BN scale/bias -------------------------------------------
__global__ __launch_bounds__(128) void k2b_fin(
    const float* __restrict__ part,
    const float* __restrict__ fg, const float* __restrict__ fb,
    const float* __restrict__ sg, const float* __restrict__ sb,
    float* __restrict__ bn)     // [af(64) cf(64) as(64) cs(64)]
{
    const int t = threadIdx.x;
    const int br = t >> 6;
    const int j  = t & 63;
    float S1 = 0.f, S2 = 0.f;
    for (int c = 0; c < 32; ++c) {
        const float* pr = part + (br * 32 + c) * 128;
        S1 += pr[j];
        S2 += pr[64 + j];
    }
    float m   = S1 * (1.0f / NB);
    float var = S2 * (1.0f / NB) - m * m;
    float g  = br ? sg[j] : fg[j];
    float be = br ? sb[j] : fb[j];
    float a  = g * rsqrtf(var + 1e-5f);
    bn[br * 128 + j]      = a;
    bn[br * 128 + 64 + j] = be - m * a;
}

// ---- k3: tail, 32 batches per block ----------------------------------------
#define K3G 32
__global__ __launch_bounds__(256) void k3_back(
    const float* __restrict__ h1, const float* __restrict__ g1,
    const float* __restrict__ bn,
    const float* __restrict__ f2_fw, const float* __restrict__ f2_fb,
    const float* __restrict__ f2_gw, const float* __restrict__ f2_gb,
    const float* __restrict__ s2_fw, const float* __restrict__ s2_fb,
    const float* __restrict__ s2_gw, const float* __restrict__ s2_gb,
    const float* __restrict__ endm,
    float* __restrict__ out_recon, float* __restrict__ out_abd,
    float* __restrict__ out_es)
{
    const int B0 = blockIdx.x * K3G;
    const int t = threadIdx.x;
    __shared__ float bnl[256];
    __shared__ float endl[PP * LL];
    __shared__ float hh[K3G * 65], gg[K3G * 65];
    __shared__ float logit[K3G * 8], esv[K3G * 8], coef[K3G * 8];

    bnl[t] = bn[t];
    for (int i = t; i < PP * LL; i += 256) endl[i] = endm[i];
    __syncthreads();

    for (int i = t; i < K3G * HID; i += 256) {
        int ba = i >> 6, j = i & 63;
        float v1 = h1[(size_t)(B0 + ba) * HID + j] * bnl[j] + bnl[64 + j];
        hh[ba * 65 + j] = v1 * f_sigmoid(v1);
        float v2 = g1[(size_t)(B0 + ba) * HID + j] * bnl[128 + j] + bnl[192 + j];
        gg[ba * 65 + j] = v2 * f_sigmoid(v2);
    }
    __syncthreads();

    for (int i = t; i < K3G * 2 * PP; i += 256) {
        int ba = i / (2 * PP);
        int rr = i - ba * (2 * PP);
        int br = rr / PP;
        int p  = rr - br * PP;
        const float* src = (br ? gg : hh) + ba * 65;
        const float* fw  = br ? s2_fw : f2_fw;
        const float* fbp = br ? s2_fb : f2_fb;
        const float* gw  = br ? s2_gw : f2_gw;
        const float* gbp = br ? s2_gb : f2_gb;
        float df = fbp[p], dg = gbp[p];
        for (int j = 0; j < HID; ++j) {
            float v = src[j];
            df = fmaf(v, fw[j * PP + p], df);
            dg = fmaf(v, gw[j * PP + p], dg);
        }
        float glu = df * f_sigmoid(dg);
        if (br == 0) {
            logit[ba * 8 + p] = glu;
        } else {
            float e = tanhf(glu);
            esv[ba * 8 + p] = e;
            out_es[(size_t)(B0 + ba) * PP + p] = e;
        }
    }
    __syncthreads();

    if (t < K3G) {
        float mx = -1e30f;
#pragma unroll
        for (int p = 0; p < PP; ++p) mx = fmaxf(mx, logit[t * 8 + p]);
        float e[PP]; float sum = 0.f;
#pragma unroll
        for (int p = 0; p < PP; ++p) { e[p] = __expf(logit[t * 8 + p] - mx); sum += e[p]; }
        float inv = 1.0f / sum;
#pragma unroll
        for (int p = 0; p < PP; ++p) {
            float a = e[p] * inv;
            out_abd[(size_t)(B0 + t) * PP + p] = a;
            coef[t * 8 + p] = a * (1.0f + 0.2f * esv[t * 8 + p]);
        }
    }
    __syncthreads();

    for (int i = t; i < K3G * LL; i += 256) {
        int ba = i / LL;
        int l  = i - ba * LL;
        float r = 0.f;
#pragma unroll
        for (int p = 0; p < PP; ++p)
            r = fmaf(coef[ba * 8 + p], endl[p * LL + l], r);
        out_recon[(size_t)(B0 + ba) * LL + l] = r;
    }
}

extern "C" void kernel_launch(void* const* d_in, const int* in_sizes, int n_in,
                              void* d_out, int out_size, void* d_ws, size_t ws_size,
                              hipStream_t stream)
{
    const float* x     = (const float*)d_in[0];
    const float* wk_w  = (const float*)d_in[1];
    const float* wk_b  = (const float*)d_in[2];
    const float* wv_w  = (const float*)d_in[3];
    const float* wv_b  = (const float*)d_in[4];
    const float* wq_w  = (const float*)d_in[5];
    const float* wq_b  = (const float*)d_in[6];
    const float* ng_w  = (const float*)d_in[7];
    const float* ng_b  = (const float*)d_in[8];
    const float* f1_fw = (const float*)d_in[9];
    const float* f1_fb = (const float*)d_in[10];
    const float* f1_gw = (const float*)d_in[11];
    const float* f1_gb = (const float*)d_in[12];
    const float* f_bng = (const float*)d_in[13];
    const float* f_bnb = (const float*)d_in[14];
    const float* f2_fw = (const float*)d_in[15];
    const float* f2_fb = (const float*)d_in[16];
    const float* f2_gw = (const float*)d_in[17];
    const float* f2_gb = (const float*)d_in[18];
    const float* s1_fw = (const float*)d_in[19];
    const float* s1_fb = (const float*)d_in[20];
    const float* s1_gw = (const float*)d_in[21];
    const float* s1_gb = (const float*)d_in[22];
    const float* s_bng = (const float*)d_in[23];
    const float* s_bnb = (const float*)d_in[24];
    const float* s2_fw = (const float*)d_in[25];
    const float* s2_fb = (const float*)d_in[26];
    const float* s2_gw = (const float*)d_in[27];
    const float* s2_gb = (const float*)d_in[28];
    const float* endm  = (const float*)d_in[29];

    float* ws    = (float*)d_ws;
    float* h1_ws = ws;                                   // NB*64 f32
    float* g1_ws = ws + (size_t)NB * HID;                // NB*64 f32
    float* bn    = ws + (size_t)2 * NB * HID;            // 256 f32
    float* part  = bn + 256;                             // 8192 f32
    ushort* wpack = (ushort*)(part + 8192);              // 86016 bf16

    float* out       = (float*)d_out;
    float* out_recon = out;                              // NB*LL
    float* out_abd   = out + (size_t)NB * LL;            // NB*PP
    float* out_es    = out + (size_t)NB * (LL + PP);     // NB*PP

    k0_pack<<<NNT, 256, 0, stream>>>(wk_w, wv_w, wq_w, wpack);
    k1_front<<<NB / GPB, 256, 0, stream>>>(x, wpack, wk_b, wv_b, wq_b,
                                           ng_w, ng_b, f1_fw, f1_fb, f1_gw, f1_gb,
                                           s1_fw, s1_fb, s1_gw, s1_gb, h1_ws, g1_ws);
    k2a_part<<<64, 256, 0, stream>>>(h1_ws, g1_ws, part);
    k2b_fin<<<1, 128, 0, stream>>>(part, f_bng, f_bnb, s_bng, s_bnb, bn);
    k3_back<<<NB / K3G, 256, 0, stream>>>(h1_ws, g1_ws, bn,
                                          f2_fw, f2_fb, f2_gw, f2_gb,
                                          s2_fw, s2_fb, s2_gw, s2_gb,
                                          endm, out_recon, out_abd, out_es);
}

// Round 5
// 405.504 us; speedup vs baseline: 2.1209x; 1.5064x over previous
//
#include <hip/hip_runtime.h>
#include <hip/hip_bf16.h>

typedef unsigned short ushort;
typedef unsigned int   uint;
typedef __bf16 bfrag_t __attribute__((ext_vector_type(8)));   // 8 bf16 = 4 VGPRs
typedef float  ffrag_t __attribute__((ext_vector_type(4)));   // 4 f32 acc

#define NB   8192   // batch
#define LL   224    // spectral bands
#define SS   25     // K*K
#define CTR  12     // center index
#define DD   128    // model dim
#define PP   6      // endmembers
#define HID  64     // hidden
#define GPB  2      // batches per kA block
#define NKC  7      // K-chunks of 32 (224/32)
#define NMT  4      // M-tiles of 16 (2 batches * 32 rows)
#define NNT  24     // n-tiles of 16 (384 cols = wk|wv|wq)
#define VST  132    // ushort LDS row stride for keys/vals (even, bank-stride 2)
#define WPK_ELEMS (NKC * NNT * 64 * 8)       // 86016
#define FC1_ELEMS (4 * 16 * 64 * 8)          // 32768

__device__ __forceinline__ float f_sigmoid(float x) { return 1.0f / (1.0f + __expf(-x)); }
__device__ __forceinline__ ushort f2bf(float f) {
    __hip_bfloat16 h = __float2bfloat16(f);
    ushort u; __builtin_memcpy(&u, &h, 2); return u;
}
__device__ __forceinline__ float bfu2f(ushort u) {
    uint v = ((uint)u) << 16; float f; __builtin_memcpy(&f, &v, 4); return f;
}

// ---- k0: pack [wk|wv|wq] (24 tiles) and [f1f|f1g|s1f|s1g] (16 tiles) -------
// B-frag: lane holds B[k = kc*32+(lane>>4)*8+j][n = nt*16+(lane&15)]
__global__ __launch_bounds__(256) void k0_pack(
    const float* __restrict__ wk_w, const float* __restrict__ wv_w,
    const float* __restrict__ wq_w,
    const float* __restrict__ f1_fw, const float* __restrict__ f1_gw,
    const float* __restrict__ s1_fw, const float* __restrict__ s1_gw,
    ushort* __restrict__ wpack, ushort* __restrict__ fc1pack)
{
    const int blk = blockIdx.x;
    if (blk < NNT) {                            // wkvq: K=224, ld=128
        const int nt  = blk;
        const int mat = nt >> 3;
        const float* w = mat == 0 ? wk_w : (mat == 1 ? wv_w : wq_w);
        const int cb = (nt & 7) * 16;
        for (int e = threadIdx.x; e < NKC * 64 * 8; e += 256) {
            int j    = e & 7;
            int lane = (e >> 3) & 63;
            int kc   = e >> 9;
            int k = kc * 32 + ((lane >> 4) << 3) + j;
            int c = cb + (lane & 15);
            wpack[((kc * NNT + nt) * 64 + lane) * 8 + j] = f2bf(w[k * DD + c]);
        }
    } else {                                    // fc1: K=128, ld=64, 4 mats
        const int nt = blk - NNT;               // 0..15
        const int m2 = nt >> 2;                 // 0:f1f 1:f1g 2:s1f 3:s1g
        const float* w = m2 == 0 ? f1_fw : (m2 == 1 ? f1_gw : (m2 == 2 ? s1_fw : s1_gw));
        const int cb = (nt & 3) * 16;
        for (int e = threadIdx.x; e < 4 * 64 * 8; e += 256) {
            int j    = e & 7;
            int lane = (e >> 3) & 63;
            int kc   = e >> 9;
            int k = kc * 32 + ((lane >> 4) << 3) + j;
            int c = cb + (lane & 15);
            fc1pack[((kc * 16 + nt) * 64 + lane) * 8 + j] = f2bf(w[k * HID + c]);
        }
    }
}

// ---- kA: MFMA K/V/Q GEMM + attention + nearby gate + swish -----------------
// 512 threads = 8 waves. Wave w: kv-nt {w (keys), w+8 (vals)}, q-nt {16+w}.
__global__ __launch_bounds__(512, 4) void kA_front(
    const float* __restrict__ x,
    const ushort* __restrict__ wpack,
    const float* __restrict__ wk_b, const float* __restrict__ wv_b,
    const float* __restrict__ wq_b,
    const float* __restrict__ ng_w, const float* __restrict__ ng_b,
    ushort* __restrict__ swv_ws)
{
    // A fragments: 4 mt * 7 kc * 64 lanes * 8 = 14336 ushort (28672 B)
    // after GEMM reused: keys[0:6600) vals[6600:13200) as [g][s][VST] ushort
    __shared__ ushort alds[NMT * NKC * 64 * 8];
    __shared__ float  qv[GPB * DD];
    __shared__ float  att[8 * 26];
    __shared__ float  red[4];

    const int t    = threadIdx.x;
    const int b0   = blockIdx.x * GPB;
    const int wave = t >> 6;
    const int lane = t & 63;

    // ---- phase 1: stage x as bf16 A-fragments (linear coalesced reads) ----
    for (int g = 0; g < GPB; ++g) {
        const float* xb = x + (size_t)(b0 + g) * (LL * SS);
        for (int i = t; i < LL * SS; i += 512) {
            int l = i / SS;
            int s = i - l * SS;
            int r  = g * 32 + s;
            int idx = (((r >> 4) * NKC + (l >> 5)) * 64 +
                       ((r & 15) | (((l >> 3) & 3) << 4))) * 8 + (l & 7);
            alds[idx] = f2bf(xb[i]);
        }
    }
    __syncthreads();

    // ---- phase 2: GEMM ----------------------------------------------------
    ffrag_t acck[NMT], accv[NMT], accq[2];
#pragma unroll
    for (int mt = 0; mt < NMT; ++mt) {
        acck[mt] = ffrag_t{0.f, 0.f, 0.f, 0.f};
        accv[mt] = ffrag_t{0.f, 0.f, 0.f, 0.f};
    }
    accq[0] = ffrag_t{0.f, 0.f, 0.f, 0.f};
    accq[1] = ffrag_t{0.f, 0.f, 0.f, 0.f};

    for (int kc = 0; kc < NKC; ++kc) {
        bfrag_t bk = *(const bfrag_t*)(wpack + ((kc * NNT + wave) * 64 + lane) * 8);
        bfrag_t bv = *(const bfrag_t*)(wpack + ((kc * NNT + wave + 8) * 64 + lane) * 8);
        bfrag_t bq = *(const bfrag_t*)(wpack + ((kc * NNT + wave + 16) * 64 + lane) * 8);
#pragma unroll
        for (int mt = 0; mt < NMT; ++mt) {
            bfrag_t af = *(const bfrag_t*)(alds + ((mt * NKC + kc) * 64 + lane) * 8);
            acck[mt] = __builtin_amdgcn_mfma_f32_16x16x32_bf16(af, bk, acck[mt], 0, 0, 0);
            accv[mt] = __builtin_amdgcn_mfma_f32_16x16x32_bf16(af, bv, accv[mt], 0, 0, 0);
            if ((mt & 1) == 0)
                accq[mt >> 1] = __builtin_amdgcn_mfma_f32_16x16x32_bf16(af, bq, accq[mt >> 1], 0, 0, 0);
        }
    }
    __syncthreads();   // all A-frag reads done; alds becomes keys/vals

    // ---- phase 2b: C tiles -> LDS bf16; q -> qv ---------------------------
    // C/D layout: col = lane&15, row = (lane>>4)*4 + reg
    {
        const int c  = wave * 16 + (lane & 15);
        const float bk = wk_b[c];
        const float bv = wv_b[c];
#pragma unroll
        for (int mt = 0; mt < NMT; ++mt) {
#pragma unroll
            for (int reg = 0; reg < 4; ++reg) {
                int r = mt * 16 + ((lane >> 4) << 2) + reg;
                int g = r >> 5;
                int s = r & 31;
                if (s < SS) {
                    alds[(g * SS + s) * VST + c]        = f2bf(acck[mt][reg] + bk);
                    alds[6600 + (g * SS + s) * VST + c] = f2bf(accv[mt][reg] + bv);
                }
            }
        }
        if ((lane >> 4) == 3) {                 // reg0 -> rows 12 (mt0) / 44 (mt2)
            float bq = wq_b[c];
            qv[c]      = accq[0][0] + bq;
            qv[DD + c] = accq[1][0] + bq;
        }
    }
    __syncthreads();

    // ---- phase 3: scores + shuffle softmax (8 rows x 32 lanes) ------------
    if (t < 256) {
        const int r   = t >> 5;                 // g*4+h
        const int g   = r >> 2;
        const int h   = r & 3;
        const int l32 = t & 31;
        float sc = -1e30f;
        if (l32 < SS) {
            const ushort* kr = alds + (g * SS + l32) * VST + h * 32;
            const float*  qr = qv + g * DD + h * 32;
            float a0 = 0.f, a1 = 0.f, a2 = 0.f, a3 = 0.f;
#pragma unroll
            for (int i = 0; i < 32; i += 4) {
                a0 = fmaf(qr[i + 0], bfu2f(kr[i + 0]), a0);
                a1 = fmaf(qr[i + 1], bfu2f(kr[i + 1]), a1);
                a2 = fmaf(qr[i + 2], bfu2f(kr[i + 2]), a2);
                a3 = fmaf(qr[i + 3], bfu2f(kr[i + 3]), a3);
            }
            sc = ((a0 + a1) + (a2 + a3)) * 0.088388347648318447f;
            if (l32 == CTR) sc -= 1e6f;
        }
        float mx = sc;
#pragma unroll
        for (int m = 16; m > 0; m >>= 1) mx = fmaxf(mx, __shfl_xor(mx, m, 32));
        float e = __expf(sc - mx);
        float sum = e;
#pragma unroll
        for (int m = 16; m > 0; m >>= 1) sum += __shfl_xor(sum, m, 32);
        if (l32 < SS) att[r * 26 + l32] = e / sum;
    }
    __syncthreads();

    // ---- phase 4: surround / central / nearby gate / swish ----------------
    if (t < 256) {
        const int g = t >> 7;
        const int d = t & 127;
        const int h = d >> 5;
        const ushort* vrow = alds + 6600 + g * SS * VST + d;
        const float* arow = att + (g * 4 + h) * 26;
        float s0 = 0.f, s1 = 0.f;
#pragma unroll
        for (int s = 0; s < 24; s += 2) {
            s0 = fmaf(arow[s],     bfu2f(vrow[s * VST]),       s0);
            s1 = fmaf(arow[s + 1], bfu2f(vrow[(s + 1) * VST]), s1);
        }
        float sur = fmaf(arow[24], bfu2f(vrow[24 * VST]), s0 + s1);
        float cen = bfu2f(vrow[CTR * VST]);
        float term = (cen - sur) * ng_w[d];
#pragma unroll
        for (int off = 32; off > 0; off >>= 1) term += __shfl_down(term, off);
        if (lane == 0) red[wave] = term;
        __syncthreads();
        float tot = red[g * 2] + red[g * 2 + 1] + ng_b[0];
        float nearby = f_sigmoid(tot);
        float ssv = cen + nearby * sur;
        float sw  = ssv * f_sigmoid(ssv);
        swv_ws[(size_t)(b0 + g) * DD + d] = f2bf(sw);
    } else {
        __syncthreads();
    }
}

// ---- kC: FC1 + GLU as batched MFMA GEMM (M=8192, K=128, N=256) -------------
// 256 blocks x 32 rows. Wave w: nt {w (f1f), w+4 (f1g), w+8 (s1f), w+12 (s1g)}
__global__ __launch_bounds__(256) void kC_fc1(
    const ushort* __restrict__ swv_ws,
    const ushort* __restrict__ fc1pack,
    const float* __restrict__ f1_fb, const float* __restrict__ f1_gb,
    const float* __restrict__ s1_fb, const float* __restrict__ s1_gb,
    float* __restrict__ h1_ws, float* __restrict__ g1_ws)
{
    const int t    = threadIdx.x;
    const int wave = t >> 6;
    const int lane = t & 63;
    const int m0   = blockIdx.x * 32;

    ffrag_t acc[4][2];
#pragma unroll
    for (int ni = 0; ni < 4; ++ni)
#pragma unroll
        for (int mt = 0; mt < 2; ++mt) acc[ni][mt] = ffrag_t{0.f, 0.f, 0.f, 0.f};

#pragma unroll
    for (int kc = 0; kc < 4; ++kc) {
        bfrag_t bf[4];
#pragma unroll
        for (int ni = 0; ni < 4; ++ni) {
            int nt = wave + 4 * ni;
            bf[ni] = *(const bfrag_t*)(fc1pack + ((kc * 16 + nt) * 64 + lane) * 8);
        }
#pragma unroll
        for (int mt = 0; mt < 2; ++mt) {
            bfrag_t af = *(const bfrag_t*)(swv_ws +
                (size_t)(m0 + mt * 16 + (lane & 15)) * DD + kc * 32 + ((lane >> 4) << 3));
#pragma unroll
            for (int ni = 0; ni < 4; ++ni)
                acc[ni][mt] = __builtin_amdgcn_mfma_f32_16x16x32_bf16(af, bf[ni], acc[ni][mt], 0, 0, 0);
        }
    }

    const int c16 = wave * 16 + (lane & 15);
    const float fb1 = f1_fb[c16], gb1 = f1_gb[c16];
    const float fb2 = s1_fb[c16], gb2 = s1_gb[c16];
#pragma unroll
    for (int mt = 0; mt < 2; ++mt) {
#pragma unroll
        for (int reg = 0; reg < 4; ++reg) {
            int m = m0 + mt * 16 + ((lane >> 4) << 2) + reg;
            float hf = acc[0][mt][reg] + fb1;
            float hg = acc[1][mt][reg] + gb1;
            float gf = acc[2][mt][reg] + fb2;
            float gg = acc[3][mt][reg] + gb2;
            h1_ws[(size_t)m * HID + c16] = hf * f_sigmoid(hg);
            g1_ws[(size_t)m * HID + c16] = gf * f_sigmoid(gg);
        }
    }
}

// ---- k2a: per-chunk partial sums (coalesced) -------------------------------
__global__ __launch_bounds__(256) void k2a_part(
    const float* __restrict__ h1, const float* __restrict__ g1,
    float* __restrict__ part)   // [2][32][128]: sum(64) | sumsq(64)
{
    const int br    = blockIdx.x >> 5;
    const int chunk = blockIdx.x & 31;
    const float* src = br ? g1 : h1;
    const int t = threadIdx.x;
    const int w = t >> 6;
    const int j = t & 63;
    const int base = chunk * 256;
    float s = 0.f, sq = 0.f;
    for (int i = 0; i < 64; ++i) {
        float v = src[(size_t)(base + i * 4 + w) * HID + j];
        s += v;
        sq = fmaf(v, v, sq);
    }
    __shared__ float ls[4][64], lq[4][64];
    ls[w][j] = s; lq[w][j] = sq;
    __syncthreads();
    if (t < 64) {
        float S = ls[0][t] + ls[1][t] + ls[2][t] + ls[3][t];
        float Q = lq[0][t] + lq[1][t] + lq[2][t] + lq[3][t];
        float* pr = part + (br * 32 + chunk) * 128;
        pr[t]      = S;
        pr[64 + t] = Q;
    }
}

// ---- k2b: finalize BN scale/bias -------------------------------------------
__global__ __launch_bounds__(128) void k2b_fin(
    const float* __restrict__ part,
    const float* __restrict__ fg, const float* __restrict__ fb,
    const float* __restrict__ sg, const float* __restrict__ sb,
    float* __restrict__ bn)     // [af(64) cf(64) as(64) cs(64)]
{
    const int t = threadIdx.x;
    const int br = t >> 6;
    const int j  = t & 63;
    float S1 = 0.f, S2 = 0.f;
#pragma unroll 8
    for (int c = 0; c < 32; ++c) {
        const float* pr = part + (br * 32 + c) * 128;
        S1 += pr[j];
        S2 += pr[64 + j];
    }
    float m   = S1 * (1.0f / NB);
    float var = S2 * (1.0f / NB) - m * m;
    float g  = br ? sg[j] : fg[j];
    float be = br ? sb[j] : fb[j];
    float a  = g * rsqrtf(var + 1e-5f);
    bn[br * 128 + j]      = a;
    bn[br * 128 + 64 + j] = be - m * a;
}

// ---- k3: tail, 32 batches per block, weights staged in LDS -----------------
#define K3G 32
__global__ __launch_bounds__(256) void k3_back(
    const float* __restrict__ h1, const float* __restrict__ g1,
    const float* __restrict__ bn,
    const float* __restrict__ f2_fw, const float* __restrict__ f2_fb,
    const float* __restrict__ f2_gw, const float* __restrict__ f2_gb,
    const float* __restrict__ s2_fw, const float* __restrict__ s2_fb,
    const float* __restrict__ s2_gw, const float* __restrict__ s2_gb,
    const float* __restrict__ endm,
    float* __restrict__ out_recon, float* __restrict__ out_abd,
    float* __restrict__ out_es)
{
    const int B0 = blockIdx.x * K3G;
    const int t = threadIdx.x;
    __shared__ float bnl[256];
    __shared__ float w2[4][HID * PP];   // f2_fw f2_gw s2_fw s2_gw
    __shared__ float b2[4][8];
    __shared__ float endl[PP * LL];
    __shared__ float hh[K3G * 65], gg[K3G * 65];
    __shared__ float logit[K3G * 8], esv[K3G * 8], coef[K3G * 8];

    bnl[t] = bn[t];
    for (int i = t; i < HID * PP; i += 256) {
        w2[0][i] = f2_fw[i];
        w2[1][i] = f2_gw[i];
        w2[2][i] = s2_fw[i];
        w2[3][i] = s2_gw[i];
    }
    if (t < PP) {
        b2[0][t] = f2_fb[t];
        b2[1][t] = f2_gb[t];
        b2[2][t] = s2_fb[t];
        b2[3][t] = s2_gb[t];
    }
    for (int i = t; i < PP * LL; i += 256) endl[i] = endm[i];
    __syncthreads();

    for (int i = t; i < K3G * HID; i += 256) {
        int ba = i >> 6, j = i & 63;
        float v1 = h1[(size_t)(B0 + ba) * HID + j] * bnl[j] + bnl[64 + j];
        hh[ba * 65 + j] = v1 * f_sigmoid(v1);
        float v2 = g1[(size_t)(B0 + ba) * HID + j] * bnl[128 + j] + bnl[192 + j];
        gg[ba * 65 + j] = v2 * f_sigmoid(v2);
    }
    __syncthreads();

    for (int i = t; i < K3G * 2 * PP; i += 256) {
        int ba = i / (2 * PP);
        int rr = i - ba * (2 * PP);
        int br = rr / PP;
        int p  = rr - br * PP;
        const float* src = (br ? gg : hh) + ba * 65;
        const float* fw  = w2[br * 2];
        const float* gw  = w2[br * 2 + 1];
        float df = b2[br * 2][p], dg = b2[br * 2 + 1][p];
#pragma unroll 8
        for (int j = 0; j < HID; ++j) {
            float v = src[j];
            df = fmaf(v, fw[j * PP + p], df);
            dg = fmaf(v, gw[j * PP + p], dg);
        }
        float glu = df * f_sigmoid(dg);
        if (br == 0) {
            logit[ba * 8 + p] = glu;
        } else {
            float e = tanhf(glu);
            esv[ba * 8 + p] = e;
            out_es[(size_t)(B0 + ba) * PP + p] = e;
        }
    }
    __syncthreads();

    if (t < K3G) {
        float mx = -1e30f;
#pragma unroll
        for (int p = 0; p < PP; ++p) mx = fmaxf(mx, logit[t * 8 + p]);
        float e[PP]; float sum = 0.f;
#pragma unroll
        for (int p = 0; p < PP; ++p) { e[p] = __expf(logit[t * 8 + p] - mx); sum += e[p]; }
        float inv = 1.0f / sum;
#pragma unroll
        for (int p = 0; p < PP; ++p) {
            float a = e[p] * inv;
            out_abd[(size_t)(B0 + t) * PP + p] = a;
            coef[t * 8 + p] = a * (1.0f + 0.2f * esv[t * 8 + p]);
        }
    }
    __syncthreads();

    for (int i = t; i < K3G * LL; i += 256) {
        int ba = i / LL;
        int l  = i - ba * LL;
        float r = 0.f;
#pragma unroll
        for (int p = 0; p < PP; ++p)
            r = fmaf(coef[ba * 8 + p], endl[p * LL + l], r);
        out_recon[(size_t)(B0 + ba) * LL + l] = r;
    }
}

extern "C" void kernel_launch(void* const* d_in, const int* in_sizes, int n_in,
                              void* d_out, int out_size, void* d_ws, size_t ws_size,
                              hipStream_t stream)
{
    const float* x     = (const float*)d_in[0];
    const float* wk_w  = (const float*)d_in[1];
    const float* wk_b  = (const float*)d_in[2];
    const float* wv_w  = (const float*)d_in[3];
    const float* wv_b  = (const float*)d_in[4];
    const float* wq_w  = (const float*)d_in[5];
    const float* wq_b  = (const float*)d_in[6];
    const float* ng_w  = (const float*)d_in[7];
    const float* ng_b  = (const float*)d_in[8];
    const float* f1_fw = (const float*)d_in[9];
    const float* f1_fb = (const float*)d_in[10];
    const float* f1_gw = (const float*)d_in[11];
    const float* f1_gb = (const float*)d_in[12];
    const float* f_bng = (const float*)d_in[13];
    const float* f_bnb = (const float*)d_in[14];
    const float* f2_fw = (const float*)d_in[15];
    const float* f2_fb = (const float*)d_in[16];
    const float* f2_gw = (const float*)d_in[17];
    const float* f2_gb = (const float*)d_in[18];
    const float* s1_fw = (const float*)d_in[19];
    const float* s1_fb = (const float*)d_in[20];
    const float* s1_gw = (const float*)d_in[21];
    const float* s1_gb = (const float*)d_in[22];
    const float* s_bng = (const float*)d_in[23];
    const float* s_bnb = (const float*)d_in[24];
    const float* s2_fw = (const float*)d_in[25];
    const float* s2_fb = (const float*)d_in[26];
    const float* s2_gw = (const float*)d_in[27];
    const float* s2_gb = (const float*)d_in[28];
    const float* endm  = (const float*)d_in[29];

    float* ws = (float*)d_ws;
    float*  h1_ws   = ws;                                   // [0, 524288)
    float*  g1_ws   = ws + (size_t)NB * HID;                // [524288, 1048576)
    float*  bn      = ws + 1048576;                         // 256
    float*  part    = ws + 1048832;                         // 8192
    ushort* wpack   = (ushort*)(ws + 1057024);              // 86016 ushort
    ushort* fc1pack = (ushort*)(ws + 1057024 + WPK_ELEMS / 2);      // 32768 ushort
    ushort* swv_ws  = (ushort*)(ws + 1057024 + (WPK_ELEMS + FC1_ELEMS) / 2); // NB*128

    float* out       = (float*)d_out;
    float* out_recon = out;                              // NB*LL
    float* out_abd   = out + (size_t)NB * LL;            // NB*PP
    float* out_es    = out + (size_t)NB * (LL + PP);     // NB*PP

    k0_pack<<<NNT + 16, 256, 0, stream>>>(wk_w, wv_w, wq_w, f1_fw, f1_gw,
                                          s1_fw, s1_gw, wpack, fc1pack);
    kA_front<<<NB / GPB, 512, 0, stream>>>(x, wpack, wk_b, wv_b, wq_b,
                                           ng_w, ng_b, swv_ws);
    kC_fc1<<<NB / 32, 256, 0, stream>>>(swv_ws, fc1pack, f1_fb, f1_gb,
                                        s1_fb, s1_gb, h1_ws, g1_ws);
    k2a_part<<<64, 256, 0, stream>>>(h1_ws, g1_ws, part);
    k2b_fin<<<1, 128, 0, stream>>>(part, f_bng, f_bnb, s_bng, s_bnb, bn);
    k3_back<<<NB / K3G, 256, 0, stream>>>(h1_ws, g1_ws, bn,
                                          f2_fw, f2_fb, f2_gw, f2_gb,
                                          s2_fw, s2_fb, s2_gw, s2_gb,
                                          endm, out_recon, out_abd, out_es);
}

// Round 6
// 369.456 us; speedup vs baseline: 2.3279x; 1.0976x over previous
//
#include <hip/hip_runtime.h>
#include <hip/hip_bf16.h>

typedef unsigned short ushort;
typedef unsigned int   uint;
typedef __bf16 bfrag_t __attribute__((ext_vector_type(8)));   // 8 bf16 = 4 VGPRs
typedef float  ffrag_t __attribute__((ext_vector_type(4)));   // 4 f32 acc

#define NB   8192   // batch
#define LL   224    // spectral bands
#define SS   25     // K*K
#define CTR  12     // center index
#define DD   128    // model dim
#define PP   6      // endmembers
#define HID  64     // hidden
#define GPB  2      // batches per kA block
#define NKC  7      // K-chunks of 32 (224/32)
#define NMT  4      // M-tiles of 16 (2 batches * 32 rows)
#define NNT  24     // n-tiles of 16 (384 cols = wk|wv|wq)
#define VST  132    // ushort LDS row stride for keys/vals
#define WPK_ELEMS (NKC * NNT * 64 * 8)       // 86016
#define FC1_ELEMS (4 * 16 * 64 * 8)          // 32768

__device__ __forceinline__ float f_sigmoid(float x) { return 1.0f / (1.0f + __expf(-x)); }
__device__ __forceinline__ ushort f2bf(float f) {
    __hip_bfloat16 h = __float2bfloat16(f);
    ushort u; __builtin_memcpy(&u, &h, 2); return u;
}
__device__ __forceinline__ float bfu2f(ushort u) {
    uint v = ((uint)u) << 16; float f; __builtin_memcpy(&f, &v, 4); return f;
}

// ---- k0: pack [wk|wv|wq] (24 tiles) + [f1f|f1g|s1f|s1g] (16 tiles); zero stats
// B-frag: lane holds B[k = kc*32+(lane>>4)*8+j][n = nt*16+(lane&15)]
__global__ __launch_bounds__(256) void k0_pack(
    const float* __restrict__ wk_w, const float* __restrict__ wv_w,
    const float* __restrict__ wq_w,
    const float* __restrict__ f1_fw, const float* __restrict__ f1_gw,
    const float* __restrict__ s1_fw, const float* __restrict__ s1_gw,
    ushort* __restrict__ wpack, ushort* __restrict__ fc1pack,
    float* __restrict__ stats)
{
    const int blk = blockIdx.x;
    if (blk == 0) stats[threadIdx.x] = 0.f;     // 256 entries, zero for kC atomics
    if (blk < NNT) {                            // wkvq: K=224, ld=128
        const int nt  = blk;
        const int mat = nt >> 3;
        const float* w = mat == 0 ? wk_w : (mat == 1 ? wv_w : wq_w);
        const int cb = (nt & 7) * 16;
        for (int e = threadIdx.x; e < NKC * 64 * 8; e += 256) {
            int j    = e & 7;
            int lane = (e >> 3) & 63;
            int kc   = e >> 9;
            int k = kc * 32 + ((lane >> 4) << 3) + j;
            int c = cb + (lane & 15);
            wpack[((kc * NNT + nt) * 64 + lane) * 8 + j] = f2bf(w[k * DD + c]);
        }
    } else {                                    // fc1: K=128, ld=64, 4 mats
        const int nt = blk - NNT;               // 0..15
        const int m2 = nt >> 2;                 // 0:f1f 1:f1g 2:s1f 3:s1g
        const float* w = m2 == 0 ? f1_fw : (m2 == 1 ? f1_gw : (m2 == 2 ? s1_fw : s1_gw));
        const int cb = (nt & 3) * 16;
        for (int e = threadIdx.x; e < 4 * 64 * 8; e += 256) {
            int j    = e & 7;
            int lane = (e >> 3) & 63;
            int kc   = e >> 9;
            int k = kc * 32 + ((lane >> 4) << 3) + j;
            int c = cb + (lane & 15);
            fc1pack[((kc * 16 + nt) * 64 + lane) * 8 + j] = f2bf(w[k * HID + c]);
        }
    }
}

// ---- kA: MFMA K/V/Q GEMM + attention + nearby gate + swish -----------------
// 512 threads = 8 waves. Wave w: kv-nt {w (keys), w+8 (vals)}, q-nt {16+w}.
__global__ __launch_bounds__(512, 4) void kA_front(
    const float* __restrict__ x,
    const ushort* __restrict__ wpack,
    const float* __restrict__ wk_b, const float* __restrict__ wv_b,
    const float* __restrict__ wq_b,
    const float* __restrict__ ng_w, const float* __restrict__ ng_b,
    ushort* __restrict__ swv_ws)
{
    // A fragments: 4 mt * 7 kc * 64 lanes * 8 = 14336 ushort (28672 B)
    // after GEMM reused: keys[0:6600) vals[6600:13200) as [g][s][VST] ushort
    __shared__ ushort alds[NMT * NKC * 64 * 8];
    __shared__ float  qv[GPB * DD];
    __shared__ float  att[8 * 26];
    __shared__ float  red[4];

    const int t    = threadIdx.x;
    const int b0   = blockIdx.x * GPB;
    const int wave = t >> 6;
    const int lane = t & 63;

    // hoisted small loads (latency overlapped with x prefetch below)
    const int cC = wave * 16 + (lane & 15);
    const float biask = wk_b[cC];
    const float biasv = wv_b[cC];
    const float biasq = wq_b[cC];
    const float ngw   = ng_w[t & 127];

    // ---- phase 1: batched x prefetch (2800 float4), then scatter ----------
    const float4* xb4 = (const float4*)(x + (size_t)b0 * (LL * SS));  // 11200 f32
    float4 xf[6];
#pragma unroll
    for (int k = 0; k < 6; ++k) {
        int q = t + k * 512;
        if (q < 2800) xf[k] = xb4[q];
    }
#pragma unroll
    for (int k = 0; k < 6; ++k) {
        int q = t + k * 512;
        if (q < 2800) {
            int e0 = q * 4;
            int g  = e0 >= 5600;
            int eb0 = e0 - g * 5600;            // float4 never crosses batch (5600%4==0)
#pragma unroll
            for (int c = 0; c < 4; ++c) {
                int eb = eb0 + c;
                int l = eb / 25;
                int s = eb - l * 25;
                int r = g * 32 + s;
                int idx = (((r >> 4) * NKC + (l >> 5)) * 64 +
                           ((r & 15) | (((l >> 3) & 3) << 4))) * 8 + (l & 7);
                float fv = c == 0 ? xf[k].x : c == 1 ? xf[k].y : c == 2 ? xf[k].z : xf[k].w;
                alds[idx] = f2bf(fv);
            }
        }
    }
    __syncthreads();

    // ---- phase 2: GEMM, B-frags software-pipelined ------------------------
    ffrag_t acck[NMT], accv[NMT], accq[2];
#pragma unroll
    for (int mt = 0; mt < NMT; ++mt) {
        acck[mt] = ffrag_t{0.f, 0.f, 0.f, 0.f};
        accv[mt] = ffrag_t{0.f, 0.f, 0.f, 0.f};
    }
    accq[0] = ffrag_t{0.f, 0.f, 0.f, 0.f};
    accq[1] = ffrag_t{0.f, 0.f, 0.f, 0.f};

    bfrag_t bk = *(const bfrag_t*)(wpack + ((0 * NNT + wave) * 64 + lane) * 8);
    bfrag_t bv = *(const bfrag_t*)(wpack + ((0 * NNT + wave + 8) * 64 + lane) * 8);
    bfrag_t bq = *(const bfrag_t*)(wpack + ((0 * NNT + wave + 16) * 64 + lane) * 8);
#pragma unroll
    for (int kc = 0; kc < NKC; ++kc) {
        bfrag_t nbk, nbv, nbq;
        if (kc + 1 < NKC) {
            nbk = *(const bfrag_t*)(wpack + (((kc + 1) * NNT + wave) * 64 + lane) * 8);
            nbv = *(const bfrag_t*)(wpack + (((kc + 1) * NNT + wave + 8) * 64 + lane) * 8);
            nbq = *(const bfrag_t*)(wpack + (((kc + 1) * NNT + wave + 16) * 64 + lane) * 8);
        }
#pragma unroll
        for (int mt = 0; mt < NMT; ++mt) {
            bfrag_t af = *(const bfrag_t*)(alds + ((mt * NKC + kc) * 64 + lane) * 8);
            acck[mt] = __builtin_amdgcn_mfma_f32_16x16x32_bf16(af, bk, acck[mt], 0, 0, 0);
            accv[mt] = __builtin_amdgcn_mfma_f32_16x16x32_bf16(af, bv, accv[mt], 0, 0, 0);
            if ((mt & 1) == 0)
                accq[mt >> 1] = __builtin_amdgcn_mfma_f32_16x16x32_bf16(af, bq, accq[mt >> 1], 0, 0, 0);
        }
        if (kc + 1 < NKC) { bk = nbk; bv = nbv; bq = nbq; }
    }
    __syncthreads();   // all A-frag reads done; alds becomes keys/vals

    // ---- phase 2b: C tiles -> LDS bf16; q -> qv ---------------------------
    // C/D layout: col = lane&15, row = (lane>>4)*4 + reg
    {
#pragma unroll
        for (int mt = 0; mt < NMT; ++mt) {
#pragma unroll
            for (int reg = 0; reg < 4; ++reg) {
                int r = mt * 16 + ((lane >> 4) << 2) + reg;
                int g = r >> 5;
                int s = r & 31;
                if (s < SS) {
                    alds[(g * SS + s) * VST + cC]        = f2bf(acck[mt][reg] + biask);
                    alds[6600 + (g * SS + s) * VST + cC] = f2bf(accv[mt][reg] + biasv);
                }
            }
        }
        if ((lane >> 4) == 3) {                 // reg0 -> rows 12 (mt0) / 44 (mt2)
            qv[cC]      = accq[0][0] + biasq;
            qv[DD + cC] = accq[1][0] + biasq;
        }
    }
    __syncthreads();

    // ---- phase 3: scores + shuffle softmax (8 rows x 32 lanes) ------------
    if (t < 256) {
        const int r   = t >> 5;                 // g*4+h
        const int g   = r >> 2;
        const int h   = r & 3;
        const int l32 = t & 31;
        float sc = -1e30f;
        if (l32 < SS) {
            const ushort* kr = alds + (g * SS + l32) * VST + h * 32;
            const float*  qr = qv + g * DD + h * 32;
            float a0 = 0.f, a1 = 0.f, a2 = 0.f, a3 = 0.f;
#pragma unroll
            for (int i = 0; i < 32; i += 4) {
                a0 = fmaf(qr[i + 0], bfu2f(kr[i + 0]), a0);
                a1 = fmaf(qr[i + 1], bfu2f(kr[i + 1]), a1);
                a2 = fmaf(qr[i + 2], bfu2f(kr[i + 2]), a2);
                a3 = fmaf(qr[i + 3], bfu2f(kr[i + 3]), a3);
            }
            sc = ((a0 + a1) + (a2 + a3)) * 0.088388347648318447f;
            if (l32 == CTR) sc -= 1e6f;
        }
        float mx = sc;
#pragma unroll
        for (int m = 16; m > 0; m >>= 1) mx = fmaxf(mx, __shfl_xor(mx, m, 32));
        float e = __expf(sc - mx);
        float sum = e;
#pragma unroll
        for (int m = 16; m > 0; m >>= 1) sum += __shfl_xor(sum, m, 32);
        if (l32 < SS) att[r * 26 + l32] = e / sum;
    }
    __syncthreads();

    // ---- phase 4: surround / central / nearby gate / swish ----------------
    if (t < 256) {
        const int g = t >> 7;
        const int d = t & 127;
        const int h = d >> 5;
        const ushort* vrow = alds + 6600 + g * SS * VST + d;
        const float* arow = att + (g * 4 + h) * 26;
        float s0 = 0.f, s1 = 0.f;
#pragma unroll
        for (int s = 0; s < 24; s += 2) {
            s0 = fmaf(arow[s],     bfu2f(vrow[s * VST]),       s0);
            s1 = fmaf(arow[s + 1], bfu2f(vrow[(s + 1) * VST]), s1);
        }
        float sur = fmaf(arow[24], bfu2f(vrow[24 * VST]), s0 + s1);
        float cen = bfu2f(vrow[CTR * VST]);
        float term = (cen - sur) * ngw;
#pragma unroll
        for (int off = 32; off > 0; off >>= 1) term += __shfl_down(term, off);
        if (lane == 0) red[wave] = term;
        __syncthreads();
        float tot = red[g * 2] + red[g * 2 + 1] + ng_b[0];
        float nearby = f_sigmoid(tot);
        float ssv = cen + nearby * sur;
        float sw  = ssv * f_sigmoid(ssv);
        swv_ws[(size_t)(b0 + g) * DD + d] = f2bf(sw);
    } else {
        __syncthreads();
    }
}

// ---- kC: FC1 + GLU as batched MFMA GEMM (M=8192, K=128, N=256) -------------
// 256 blocks x 32 rows; fused BN partial-sum accumulation via atomics.
// stats layout: [h_sum(64) | h_sq(64) | g_sum(64) | g_sq(64)]
__global__ __launch_bounds__(256) void kC_fc1(
    const ushort* __restrict__ swv_ws,
    const ushort* __restrict__ fc1pack,
    const float* __restrict__ f1_fb, const float* __restrict__ f1_gb,
    const float* __restrict__ s1_fb, const float* __restrict__ s1_gb,
    float* __restrict__ h1_ws, float* __restrict__ g1_ws,
    float* __restrict__ stats)
{
    const int t    = threadIdx.x;
    const int wave = t >> 6;
    const int lane = t & 63;
    const int m0   = blockIdx.x * 32;
    const int c16  = wave * 16 + (lane & 15);

    const float fb1 = f1_fb[c16], gb1 = f1_gb[c16];
    const float fb2 = s1_fb[c16], gb2 = s1_gb[c16];

    ffrag_t acc[4][2];
#pragma unroll
    for (int ni = 0; ni < 4; ++ni)
#pragma unroll
        for (int mt = 0; mt < 2; ++mt) acc[ni][mt] = ffrag_t{0.f, 0.f, 0.f, 0.f};

#pragma unroll
    for (int kc = 0; kc < 4; ++kc) {
        bfrag_t bf[4];
#pragma unroll
        for (int ni = 0; ni < 4; ++ni) {
            int nt = wave + 4 * ni;
            bf[ni] = *(const bfrag_t*)(fc1pack + ((kc * 16 + nt) * 64 + lane) * 8);
        }
#pragma unroll
        for (int mt = 0; mt < 2; ++mt) {
            bfrag_t af = *(const bfrag_t*)(swv_ws +
                (size_t)(m0 + mt * 16 + (lane & 15)) * DD + kc * 32 + ((lane >> 4) << 3));
#pragma unroll
            for (int ni = 0; ni < 4; ++ni)
                acc[ni][mt] = __builtin_amdgcn_mfma_f32_16x16x32_bf16(af, bf[ni], acc[ni][mt], 0, 0, 0);
        }
    }

    float hs = 0.f, hq = 0.f, gs = 0.f, gq = 0.f;
#pragma unroll
    for (int mt = 0; mt < 2; ++mt) {
#pragma unroll
        for (int reg = 0; reg < 4; ++reg) {
            int m = m0 + mt * 16 + ((lane >> 4) << 2) + reg;
            float hv = (acc[0][mt][reg] + fb1) * f_sigmoid(acc[1][mt][reg] + gb1);
            float gv = (acc[2][mt][reg] + fb2) * f_sigmoid(acc[3][mt][reg] + gb2);
            h1_ws[(size_t)m * HID + c16] = hv;
            g1_ws[(size_t)m * HID + c16] = gv;
            hs += hv; hq = fmaf(hv, hv, hq);
            gs += gv; gq = fmaf(gv, gv, gq);
        }
    }
    // reduce across the 4 row-groups (lanes sharing c16): xor 16, 32
    hs += __shfl_xor(hs, 16); hs += __shfl_xor(hs, 32);
    hq += __shfl_xor(hq, 16); hq += __shfl_xor(hq, 32);
    gs += __shfl_xor(gs, 16); gs += __shfl_xor(gs, 32);
    gq += __shfl_xor(gq, 16); gq += __shfl_xor(gq, 32);
    const int cg = lane >> 4;                   // 0:hs 1:hq 2:gs 3:gq
    float val = cg == 0 ? hs : cg == 1 ? hq : cg == 2 ? gs : gq;
    atomicAdd(&stats[cg * 64 + c16], val);
}

// ---- k3: tail, 32 batches per block; BN finalize inlined -------------------
#define K3G 32
__global__ __launch_bounds__(256) void k3_back(
    const float* __restrict__ h1, const float* __restrict__ g1,
    const float* __restrict__ stats,
    const float* __restrict__ f_bng, const float* __restrict__ f_bnb,
    const float* __restrict__ s_bng, const float* __restrict__ s_bnb,
    const float* __restrict__ f2_fw, const float* __restrict__ f2_fb,
    const float* __restrict__ f2_gw, const float* __restrict__ f2_gb,
    const float* __restrict__ s2_fw, const float* __restrict__ s2_fb,
    const float* __restrict__ s2_gw, const float* __restrict__ s2_gb,
    const float* __restrict__ endm,
    float* __restrict__ out_recon, float* __restrict__ out_abd,
    float* __restrict__ out_es)
{
    const int B0 = blockIdx.x * K3G;
    const int t = threadIdx.x;
    __shared__ float bnl[256];
    __shared__ float w2[4][HID * PP];   // f2_fw f2_gw s2_fw s2_gw
    __shared__ float b2[4][8];
    __shared__ float endl[PP * LL];
    __shared__ float hh[K3G * 65], gg[K3G * 65];
    __shared__ float logit[K3G * 8], esv[K3G * 8], coef[K3G * 8];

    if (t < 128) {                      // BN finalize (redundant per block, cheap)
        int br = t >> 6, j = t & 63;
        float S1 = stats[br * 128 + j];
        float S2 = stats[br * 128 + 64 + j];
        float m   = S1 * (1.0f / NB);
        float var = S2 * (1.0f / NB) - m * m;
        float gam = br ? s_bng[j] : f_bng[j];
        float be  = br ? s_bnb[j] : f_bnb[j];
        float a   = gam * rsqrtf(var + 1e-5f);
        bnl[br * 128 + j]      = a;
        bnl[br * 128 + 64 + j] = be - m * a;
    }
    for (int i = t; i < HID * PP; i += 256) {
        w2[0][i] = f2_fw[i];
        w2[1][i] = f2_gw[i];
        w2[2][i] = s2_fw[i];
        w2[3][i] = s2_gw[i];
    }
    if (t < PP) {
        b2[0][t] = f2_fb[t];
        b2[1][t] = f2_gb[t];
        b2[2][t] = s2_fb[t];
        b2[3][t] = s2_gb[t];
    }
    for (int i = t; i < PP * LL; i += 256) endl[i] = endm[i];
    __syncthreads();

    for (int i = t; i < K3G * HID; i += 256) {
        int ba = i >> 6, j = i & 63;
        float v1 = h1[(size_t)(B0 + ba) * HID + j] * bnl[j] + bnl[64 + j];
        hh[ba * 65 + j] = v1 * f_sigmoid(v1);
        float v2 = g1[(size_t)(B0 + ba) * HID + j] * bnl[128 + j] + bnl[192 + j];
        gg[ba * 65 + j] = v2 * f_sigmoid(v2);
    }
    __syncthreads();

    for (int i = t; i < K3G * 2 * PP; i += 256) {
        int ba = i / (2 * PP);
        int rr = i - ba * (2 * PP);
        int br = rr / PP;
        int p  = rr - br * PP;
        const float* src = (br ? gg : hh) + ba * 65;
        const float* fw  = w2[br * 2];
        const float* gw  = w2[br * 2 + 1];
        float df = b2[br * 2][p], dg = b2[br * 2 + 1][p];
#pragma unroll 8
        for (int j = 0; j < HID; ++j) {
            float v = src[j];
            df = fmaf(v, fw[j * PP + p], df);
            dg = fmaf(v, gw[j * PP + p], dg);
        }
        float glu = df * f_sigmoid(dg);
        if (br == 0) {
            logit[ba * 8 + p] = glu;
        } else {
            float e = tanhf(glu);
            esv[ba * 8 + p] = e;
            out_es[(size_t)(B0 + ba) * PP + p] = e;
        }
    }
    __syncthreads();

    if (t < K3G) {
        float mx = -1e30f;
#pragma unroll
        for (int p = 0; p < PP; ++p) mx = fmaxf(mx, logit[t * 8 + p]);
        float e[PP]; float sum = 0.f;
#pragma unroll
        for (int p = 0; p < PP; ++p) { e[p] = __expf(logit[t * 8 + p] - mx); sum += e[p]; }
        float inv = 1.0f / sum;
#pragma unroll
        for (int p = 0; p < PP; ++p) {
            float a = e[p] * inv;
            out_abd[(size_t)(B0 + t) * PP + p] = a;
            coef[t * 8 + p] = a * (1.0f + 0.2f * esv[t * 8 + p]);
        }
    }
    __syncthreads();

    for (int i = t; i < K3G * LL; i += 256) {
        int ba = i / LL;
        int l  = i - ba * LL;
        float r = 0.f;
#pragma unroll
        for (int p = 0; p < PP; ++p)
            r = fmaf(coef[ba * 8 + p], endl[p * LL + l], r);
        out_recon[(size_t)(B0 + ba) * LL + l] = r;
    }
}

extern "C" void kernel_launch(void* const* d_in, const int* in_sizes, int n_in,
                              void* d_out, int out_size, void* d_ws, size_t ws_size,
                              hipStream_t stream)
{
    const float* x     = (const float*)d_in[0];
    const float* wk_w  = (const float*)d_in[1];
    const float* wk_b  = (const float*)d_in[2];
    const float* wv_w  = (const float*)d_in[3];
    const float* wv_b  = (const float*)d_in[4];
    const float* wq_w  = (const float*)d_in[5];
    const float* wq_b  = (const float*)d_in[6];
    const float* ng_w  = (const float*)d_in[7];
    const float* ng_b  = (const float*)d_in[8];
    const float* f1_fw = (const float*)d_in[9];
    const float* f1_fb = (const float*)d_in[10];
    const float* f1_gw = (const float*)d_in[11];
    const float* f1_gb = (const float*)d_in[12];
    const float* f_bng = (const float*)d_in[13];
    const float* f_bnb = (const float*)d_in[14];
    const float* f2_fw = (const float*)d_in[15];
    const float* f2_fb = (const float*)d_in[16];
    const float* f2_gw = (const float*)d_in[17];
    const float* f2_gb = (const float*)d_in[18];
    const float* s1_fw = (const float*)d_in[19];
    const float* s1_fb = (const float*)d_in[20];
    const float* s1_gw = (const float*)d_in[21];
    const float* s1_gb = (const float*)d_in[22];
    const float* s_bng = (const float*)d_in[23];
    const float* s_bnb = (const float*)d_in[24];
    const float* s2_fw = (const float*)d_in[25];
    const float* s2_fb = (const float*)d_in[26];
    const float* s2_gw = (const float*)d_in[27];
    const float* s2_gb = (const float*)d_in[28];
    const float* endm  = (const float*)d_in[29];

    float* ws = (float*)d_ws;
    float*  h1_ws   = ws;                                   // NB*64
    float*  g1_ws   = ws + (size_t)NB * HID;                // NB*64
    float*  stats   = ws + 1048576;                         // 256
    ushort* wpack   = (ushort*)(ws + 1048832);              // 86016 ushort
    ushort* fc1pack = (ushort*)(ws + 1048832 + WPK_ELEMS / 2);          // 32768 ushort
    ushort* swv_ws  = (ushort*)(ws + 1048832 + (WPK_ELEMS + FC1_ELEMS) / 2); // NB*128

    float* out       = (float*)d_out;
    float* out_recon = out;                              // NB*LL
    float* out_abd   = out + (size_t)NB * LL;            // NB*PP
    float* out_es    = out + (size_t)NB * (LL + PP);     // NB*PP

    k0_pack<<<NNT + 16, 256, 0, stream>>>(wk_w, wv_w, wq_w, f1_fw, f1_gw,
                                          s1_fw, s1_gw, wpack, fc1pack, stats);
    kA_front<<<NB / GPB, 512, 0, stream>>>(x, wpack, wk_b, wv_b, wq_b,
                                           ng_w, ng_b, swv_ws);
    kC_fc1<<<NB / 32, 256, 0, stream>>>(swv_ws, fc1pack, f1_fb, f1_gb,
                                        s1_fb, s1_gb, h1_ws, g1_ws, stats);
    k3_back<<<NB / K3G, 256, 0, stream>>>(h1_ws, g1_ws, stats,
                                          f_bng, f_bnb, s_bng, s_bnb,
                                          f2_fw, f2_fb, f2_gw, f2_gb,
                                          s2_fw, s2_fb, s2_gw, s2_gb,
                                          endm, out_recon, out_abd, out_es);
}